// Round 3
// baseline (608.540 us; speedup 1.0000x reference)
//
#include <hip/hip_runtime.h>
#include <hip/hip_bf16.h>
#include <math.h>

typedef unsigned short u16;
typedef unsigned int u32;
typedef __attribute__((ext_vector_type(8))) short short8;
typedef __attribute__((ext_vector_type(4))) float f32x4;

#define MFMA16(a,b,c) __builtin_amdgcn_mfma_f32_16x16x32_bf16((a),(b),(c),0,0,0)

// ---------- helpers ----------
__device__ __forceinline__ u16 f2bf(float f) {
  u32 u = __float_as_uint(f);
  u32 r = (u + 0x7FFFu + ((u >> 16) & 1u)) >> 16;
  return (u16)r;
}
__device__ __forceinline__ float bf2f(u16 h) { return __uint_as_float(((u32)h) << 16); }
__device__ __forceinline__ void f2hl(float f, u16& h, u16& l) {
  h = f2bf(f);
  l = f2bf(f - bf2f(h));
}
__device__ __forceinline__ float wsum64(float v) {
#pragma unroll
  for (int off = 32; off > 0; off >>= 1) v += __shfl_xor(v, off, 64);
  return v;
}
// DPP wave-64 sum: row_shr 1/2/4/8 + row_bcast15/31; total lands in lane 63,
// broadcast via readlane -> SGPR.
__device__ __forceinline__ float wred64(float v) {
  v += __int_as_float(__builtin_amdgcn_update_dpp(0, __float_as_int(v), 0x111, 0xf, 0xf, true));
  v += __int_as_float(__builtin_amdgcn_update_dpp(0, __float_as_int(v), 0x112, 0xf, 0xf, true));
  v += __int_as_float(__builtin_amdgcn_update_dpp(0, __float_as_int(v), 0x114, 0xf, 0xf, true));
  v += __int_as_float(__builtin_amdgcn_update_dpp(0, __float_as_int(v), 0x118, 0xf, 0xf, true));
  v += __int_as_float(__builtin_amdgcn_update_dpp(0, __float_as_int(v), 0x142, 0xa, 0xf, true));
  v += __int_as_float(__builtin_amdgcn_update_dpp(0, __float_as_int(v), 0x143, 0xc, 0xf, true));
  return __int_as_float(__builtin_amdgcn_readlane(__float_as_int(v), 63));
}
__device__ __forceinline__ short8 s8zero() {
  short8 v;
#pragma unroll
  for (int j = 0; j < 8; ++j) v[j] = 0;
  return v;
}

// ---------- kernel 0: cast inputs to bf16 (xb, Wcat[4224x1024], Wob) ----------
// chunks: xb 2097152, Wcat 1081344, Wob 262144  => total 3440640 = 13440*256
__global__ __launch_bounds__(256) void k_cast(
    const float* __restrict__ x, const float* __restrict__ Wq, const float* __restrict__ Wk,
    const float* __restrict__ Wv, const float* __restrict__ Wg, const float* __restrict__ lrw,
    const float* __restrict__ Wo, u16* __restrict__ xb, u16* __restrict__ Wcat, u16* __restrict__ Wob) {
  int c = blockIdx.x * 256 + threadIdx.x;
  float4 v = make_float4(0.f, 0.f, 0.f, 0.f);
  u16* dst;
  if (c < 2097152) {
    v = *(const float4*)(x + (size_t)c * 4);
    dst = xb + (size_t)c * 4;
  } else if (c < 2097152 + 1081344) {
    int c2 = c - 2097152;
    int base = c2 * 4;
    int nr = base >> 10, col = base & 1023;
    if (nr < 1024)      v = *(const float4*)(Wq  + (size_t)nr * 1024 + col);
    else if (nr < 2048) v = *(const float4*)(Wk  + (size_t)(nr - 1024) * 1024 + col);
    else if (nr < 3072) v = *(const float4*)(Wv  + (size_t)(nr - 2048) * 1024 + col);
    else if (nr < 4096) v = *(const float4*)(Wg  + (size_t)(nr - 3072) * 1024 + col);
    else if (nr < 4112) v = *(const float4*)(lrw + (size_t)(nr - 4096) * 1024 + col);
    // rows 4112..4223 stay zero (N padding)
    dst = Wcat + (size_t)base;
  } else {
    int c2 = c - (2097152 + 1081344);
    v = *(const float4*)(Wo + (size_t)c2 * 4);
    dst = Wob + (size_t)c2 * 4;
  }
  ushort4 o;
  o.x = f2bf(v.x); o.y = f2bf(v.y); o.z = f2bf(v.z); o.w = f2bf(v.w);
  *(ushort4*)dst = o;
}

// ---------- shared GEMM core: C[8192-tile x N-tile] = A @ B^T, bf16 MFMA ----------
// A: [M][1024] bf16 row-major, Bw: [N][1024] bf16 row-major (both K-contiguous, NT GEMM)
// 128x128 tile, BK=32, 4 waves each 64x64 (4x4 of 16x16 tiles)
__device__ __forceinline__ void gemm_core(const u16* __restrict__ A, const u16* __restrict__ Bw,
                                          int bm, int bn, u16* sA, u16* sB, f32x4 acc[4][4]) {
  int tid = threadIdx.x;
  int lane = tid & 63, wid = tid >> 6;
  int fr = lane & 15, qd = lane >> 4;
  int wm = (wid & 1) * 64, wn = (wid >> 1) * 64;
#pragma unroll
  for (int i = 0; i < 4; ++i)
#pragma unroll
    for (int j = 0; j < 4; ++j) {
      f32x4 zz = {0.f, 0.f, 0.f, 0.f};
      acc[i][j] = zz;
    }
  for (int k0 = 0; k0 < 1024; k0 += 32) {
    __syncthreads();
#pragma unroll
    for (int cc = 0; cc < 2; ++cc) {
      int ch = tid + cc * 256;
      int row = ch >> 2, kp = (ch & 3) << 3;
      *(uint4*)(sA + row * 40 + kp) = *(const uint4*)(A + (size_t)(bm * 128 + row) * 1024 + k0 + kp);
      *(uint4*)(sB + row * 40 + kp) = *(const uint4*)(Bw + (size_t)(bn * 128 + row) * 1024 + k0 + kp);
    }
    __syncthreads();
    short8 af[4], bfr[4];
#pragma unroll
    for (int i = 0; i < 4; ++i) af[i] = *(const short8*)(sA + (wm + i * 16 + fr) * 40 + qd * 8);
#pragma unroll
    for (int j = 0; j < 4; ++j) bfr[j] = *(const short8*)(sB + (wn + j * 16 + fr) * 40 + qd * 8);
#pragma unroll
    for (int i = 0; i < 4; ++i)
#pragma unroll
      for (int j = 0; j < 4; ++j) acc[i][j] = MFMA16(af[i], bfr[j], acc[i][j]);
  }
}

// ---------- kernel 1: fused QKV + gate + lr projection ----------
__global__ __launch_bounds__(256) void k_gemm1(
    const u16* __restrict__ A, const u16* __restrict__ Bw,
    float* __restrict__ Qf, float* __restrict__ Kf, float* __restrict__ Vf,
    u16* __restrict__ gateb, float* __restrict__ eta,
    const float* __restrict__ lr_b, const float* __restrict__ tio) {
  __shared__ __align__(16) u16 sA[128 * 40];
  __shared__ __align__(16) u16 sB[128 * 40];
  int bm = blockIdx.x & 63, bn = blockIdx.x >> 6;
  f32x4 acc[4][4];
  gemm_core(A, Bw, bm, bn, sA, sB, acc);
  int tid = threadIdx.x, lane = tid & 63, wid = tid >> 6;
  int fr = lane & 15, qd = lane >> 4;
  int wm = (wid & 1) * 64, wn = (wid >> 1) * 64;
#pragma unroll
  for (int i = 0; i < 4; ++i) {
    int gr0 = bm * 128 + wm + i * 16 + qd * 4;
#pragma unroll
    for (int j = 0; j < 4; ++j) {
      int gc = bn * 128 + wn + j * 16 + fr;
      if (gc < 3072) {
        int p = gc >> 10, rem = gc & 1023, hd = rem >> 6, dd = rem & 63;
        float* dst = (p == 0) ? Qf : ((p == 1) ? Kf : Vf);
#pragma unroll
        for (int r = 0; r < 4; ++r) {
          int gr = gr0 + r;
          int b_ = gr >> 11, s = gr & 2047;
          dst[(((size_t)(b_ * 16 + hd)) * 2048 + s) * 64 + dd] = acc[i][j][r];
        }
      } else if (gc < 4096) {
        int j2 = gc - 3072;
#pragma unroll
        for (int r = 0; r < 4; ++r) {
          int gr = gr0 + r;
          float vv = acc[i][j][r];
          float gl = 0.5f * vv * (1.0f + erff(vv * 0.70710678118654752f));  // exact gelu
          gateb[(size_t)gr * 1024 + j2] = f2bf(gl);
        }
      } else if (gc < 4112) {
        int hd = gc - 4096;
        float lb = lr_b[hd];
#pragma unroll
        for (int r = 0; r < 4; ++r) {
          int gr = gr0 + r;
          int b_ = gr >> 11, s = gr & 2047, m = s & 15;
          float lm = 1.0f / (1.0f + expf(-(acc[i][j][r] + lb)));
          float tok = fmaxf(1.0f / (float)(m + 1) + tio[m], 0.0f);
          eta[((size_t)(b_ * 16 + hd)) * 2048 + s] = tok * lm * 0.015625f;  // /D
        }
      }
    }
  }
}

// ---------- kernel 2: Phase A — sequential W/b trajectory per head ----------
// R3 restructure: re-associated scan -> ONE barrier per step.
//   z^{n+1} = K^{n+1} W_n - 0.25 * sum_b D[b] u_b + b_{n+1},  D[b] = k^{n+1}_w . k^n_b
// Pre-barrier (off critical path): snapshot stores, 1-ahead vector prefetch,
//   partials K^{n+1}W_n (s_load set A), D-dots, LN-vjp on z^n -> u.
// Post-barrier: u exchange, z^{n+1} assembly, W update (s_load set B, K$ hit).
__global__ __launch_bounds__(256) void k_phaseA(
    const float* __restrict__ Kf, const float* __restrict__ Vf, const float* __restrict__ eta,
    const float* __restrict__ W_init, const float* __restrict__ b_init,
    const float* __restrict__ ttt_w, const float* __restrict__ ttt_b,
    float* __restrict__ Wseq, float* __restrict__ bseq) {
  __shared__ float pbuf[2][4][4][64];  // [buf][d-slice wave][batch][e]
  __shared__ float ush[2][4][64];      // [buf][batch][e]
  int h = blockIdx.x;
  int tid = threadIdx.x, lane = tid & 63;
  int wu = __builtin_amdgcn_readfirstlane(tid >> 6);  // wave-uniform wave id
  int wu16 = wu * 16;
  float Wreg[16];
#pragma unroll
  for (int i = 0; i < 16; ++i) Wreg[i] = W_init[(size_t)h * 4096 + (wu16 + i) * 64 + lane];
  float bcur = b_init[h * 64 + lane];
  float g = ttt_w[h * 64 + lane], tb = ttt_b[h * 64 + lane];
  // uniform last-row bases (batch 0..3); row n at offset n*1024 floats
  const float* kb0 = Kf + (((size_t)(0 * 16 + h)) * 2048 + 15) * 64;
  const float* kb1 = Kf + (((size_t)(1 * 16 + h)) * 2048 + 15) * 64;
  const float* kb2 = Kf + (((size_t)(2 * 16 + h)) * 2048 + 15) * 64;
  const float* kb3 = Kf + (((size_t)(3 * 16 + h)) * 2048 + 15) * 64;
  const float* vbw = Vf + (((size_t)(wu * 16 + h)) * 2048 + 15) * 64;
  const float* erow = eta + ((size_t)(wu * 16 + h)) * 2048 + 15;  // erow[n*16]

  // ---- prologue: z^0 = K^0 W_0 + b_0 ----
  {
    float p0 = 0.f, p1 = 0.f, p2 = 0.f, p3 = 0.f;
#pragma unroll
    for (int i = 0; i < 16; ++i) {
      float wr = Wreg[i];
      p0 += kb0[wu16 + i] * wr;
      p1 += kb1[wu16 + i] * wr;
      p2 += kb2[wu16 + i] * wr;
      p3 += kb3[wu16 + i] * wr;
    }
    pbuf[0][wu][0][lane] = p0; pbuf[0][wu][1][lane] = p1;
    pbuf[0][wu][2][lane] = p2; pbuf[0][wu][3][lane] = p3;
  }
  float kc0 = kb0[lane], kc1 = kb1[lane], kc2 = kb2[lane], kc3 = kb3[lane];
  float vcur = vbw[lane];
  float ecur = erow[0];
  __syncthreads();
  float zc = pbuf[0][0][wu][lane] + pbuf[0][1][wu][lane] +
             pbuf[0][2][wu][lane] + pbuf[0][3][wu][lane] + bcur;

  for (int n = 0; n < 128; ++n) {
    int bi = n & 1, pi = (n + 1) & 1;
    int nn = (n < 127) ? n + 1 : 127;
    size_t noff = (size_t)n * 1024, nnoff = (size_t)nn * 1024;
    // A. snapshot W_n / b_n (issued early; drain overlaps this step's work)
    {
      float* wdst = Wseq + (((size_t)h * 128 + n) * 64 + lane) * 64 + wu16;
#pragma unroll
      for (int i = 0; i < 16; i += 4) {
        float4 t4;
        t4.x = Wreg[i]; t4.y = Wreg[i + 1]; t4.z = Wreg[i + 2]; t4.w = Wreg[i + 3];
        *(float4*)(wdst + i) = t4;
      }
      if (wu == 0) bseq[((size_t)h * 128 + n) * 64 + lane] = bcur;
    }
    // B. 1-ahead vector prefetch (lane-resident rows for step nn)
    float kn0 = kb0[nnoff + lane], kn1 = kb1[nnoff + lane];
    float kn2 = kb2[nnoff + lane], kn3 = kb3[nnoff + lane];
    float vnx = vbw[nnoff + lane];
    float enx = erow[nn * 16];  // uniform -> s_load
    // C/D. partials K^{nn} . W_n over this wave's d-slice (s_load set A)
    {
      float p0 = 0.f, p1 = 0.f, p2 = 0.f, p3 = 0.f;
#pragma unroll
      for (int i = 0; i < 16; ++i) {
        float wr = Wreg[i];
        p0 += kb0[nnoff + wu16 + i] * wr;
        p1 += kb1[nnoff + wu16 + i] * wr;
        p2 += kb2[nnoff + wu16 + i] * wr;
        p3 += kb3[nnoff + wu16 + i] * wr;
      }
      pbuf[pi][wu][0][lane] = p0; pbuf[pi][wu][1][lane] = p1;
      pbuf[pi][wu][2][lane] = p2; pbuf[pi][wu][3][lane] = p3;
    }
    // F. D-dots: own next-row against all current rows
    float kon = (wu == 0) ? kn0 : (wu == 1) ? kn1 : (wu == 2) ? kn2 : kn3;
    float D0 = wred64(kon * kc0), D1 = wred64(kon * kc1);
    float D2 = wred64(kon * kc2), D3 = wred64(kon * kc3);
    // G. LN-vjp on z^n (wave wu handles batch wu's last row)
    float kl = (wu == 0) ? kc0 : (wu == 1) ? kc1 : (wu == 2) ? kc2 : kc3;
    float s1 = wred64(zc), s2 = wred64(zc * zc);
    float mu = s1 * 0.015625f;
    float var = s2 * 0.015625f - mu * mu;
    float rstd = rsqrtf(var + 1e-5f);
    float xc = zc - mu;
    float ln = xc * rstd * g + tb;
    float go = ln - (vcur - kl);
    float gxn = go * g;
    float sa = wred64(gxn * xc), sb_ = wred64(gxn);
    float gvar = -0.5f * sa * rstd * rstd * rstd;
    float gmu = -sb_ * rstd;  // sum(xc) term ~0, dropped
    float gz = gxn * rstd + gvar * 2.0f * xc * 0.015625f + gmu * 0.015625f;
    ush[bi][wu][lane] = ecur * gz;
    __syncthreads();
    // H. u exchange; b update; z^{n+1} assembly
    float u0 = ush[bi][0][lane], u1 = ush[bi][1][lane];
    float u2 = ush[bi][2][lane], u3 = ush[bi][3][lane];
    float bnext = bcur - 0.25f * (u0 + u1 + u2 + u3);
    float zsum = pbuf[pi][0][wu][lane] + pbuf[pi][1][wu][lane] +
                 pbuf[pi][2][wu][lane] + pbuf[pi][3][wu][lane];
    zc = zsum - 0.25f * (D0 * u0 + D1 * u1 + D2 * u2 + D3 * u3) + bnext;
    // I. W update with k^n slices (s_load set B — K$ hit from last iter)
#pragma unroll
    for (int i = 0; i < 16; ++i) {
      float a = kb0[noff + wu16 + i] * u0 + kb1[noff + wu16 + i] * u1 +
                kb2[noff + wu16 + i] * u2 + kb3[noff + wu16 + i] * u3;
      Wreg[i] -= 0.25f * a;
    }
    // J. rotate prefetch buffers
    kc0 = kn0; kc1 = kn1; kc2 = kn2; kc3 = kn3;
    vcur = vnx; ecur = enx; bcur = bnext;
  }
}

// ---------- kernel 3: Phase B — per-(minibatch, head) full outputs via MFMA hi/lo ----------
__global__ __launch_bounds__(256) void k_phaseB(
    const float* __restrict__ Qf, const float* __restrict__ Kf, const float* __restrict__ Vf,
    const float* __restrict__ eta, const float* __restrict__ Wseq, const float* __restrict__ bseq,
    const float* __restrict__ ttt_w, const float* __restrict__ ttt_b, float* __restrict__ yout) {
  __shared__ __align__(16) u16 WtH[64 * 72], WtL[64 * 72];   // W^T [e][d] hi/lo bf16, pad 72
  __shared__ __align__(16) u16 gzH[4][64 * 24], gzL[4][64 * 24];  // gZ^T [e][m] per wave
  __shared__ __align__(16) float At[4][16 * 20];             // Attn^T [n][m] per wave
  __shared__ float bsh[64];
  int bx = blockIdx.x;
  int n = bx & 127, h = bx >> 7;
  int tid = threadIdx.x, lane = tid & 63, wv = tid >> 6;  // wave = batch
  int fr = lane & 15, qd = lane >> 4;

  // stage W_n (already [e][d]) -> hi/lo bf16 LDS
  {
    int e = tid >> 2, d0 = (tid & 3) << 4;
    const float* src = Wseq + (((size_t)h * 128 + n) * 64 + e) * 64 + d0;
#pragma unroll
    for (int gsub = 0; gsub < 2; ++gsub) {
      u16 hb[8], lb_[8];
#pragma unroll
      for (int i = 0; i < 8; i += 4) {
        float4 v = *(const float4*)(src + gsub * 8 + i);
        f2hl(v.x, hb[i], lb_[i]);
        f2hl(v.y, hb[i + 1], lb_[i + 1]);
        f2hl(v.z, hb[i + 2], lb_[i + 2]);
        f2hl(v.w, hb[i + 3], lb_[i + 3]);
      }
      uint4 ph, pl;
      ph.x = hb[0] | ((u32)hb[1] << 16); ph.y = hb[2] | ((u32)hb[3] << 16);
      ph.z = hb[4] | ((u32)hb[5] << 16); ph.w = hb[6] | ((u32)hb[7] << 16);
      pl.x = lb_[0] | ((u32)lb_[1] << 16); pl.y = lb_[2] | ((u32)lb_[3] << 16);
      pl.z = lb_[4] | ((u32)lb_[5] << 16); pl.w = lb_[6] | ((u32)lb_[7] << 16);
      *(uint4*)(&WtH[e * 72 + d0 + gsub * 8]) = ph;
      *(uint4*)(&WtL[e * 72 + d0 + gsub * 8]) = pl;
    }
    if (tid < 64) bsh[tid] = bseq[((size_t)h * 128 + n) * 64 + tid];
  }
  __syncthreads();

  const size_t bh = (size_t)(wv * 16 + h);
  const float* Qp = Qf + (bh * 2048 + (size_t)n * 16) * 64;
  const float* Kp = Kf + (bh * 2048 + (size_t)n * 16) * 64;
  const float* Vp = Vf + (bh * 2048 + (size_t)n * 16) * 64;
  const float* ep = eta + bh * 2048 + n * 16;

  // Q/K A-operand fragments (also reused as B for Attn): [m=fr][k = s*32 + qd*8 + j]
  short8 qH[2], qL[2], kH[2], kL[2];
#pragma unroll
  for (int s = 0; s < 2; ++s) {
    const float* p1 = Qp + fr * 64 + s * 32 + qd * 8;
    const float* p2 = Kp + fr * 64 + s * 32 + qd * 8;
#pragma unroll
    for (int j = 0; j < 8; ++j) {
      u16 hb, lb_;
      f2hl(p1[j], hb, lb_); qH[s][j] = (short)hb; qL[s][j] = (short)lb_;
      f2hl(p2[j], hb, lb_); kH[s][j] = (short)hb; kL[s][j] = (short)lb_;
    }
  }

  // Z = K@W + b  (C-layout: row m = qd*4+r, col e = t*16+fr)
  f32x4 Zt[4];
#pragma unroll
  for (int t = 0; t < 4; ++t) {
    f32x4 a = {0.f, 0.f, 0.f, 0.f};
#pragma unroll
    for (int s = 0; s < 2; ++s) {
      short8 wH = *(const short8*)(&WtH[(t * 16 + fr) * 72 + s * 32 + qd * 8]);
      short8 wL = *(const short8*)(&WtL[(t * 16 + fr) * 72 + s * 32 + qd * 8]);
      a = MFMA16(kH[s], wH, a);
      a = MFMA16(kL[s], wH, a);
      a = MFMA16(kH[s], wL, a);
    }
    float bv = bsh[t * 16 + fr];
    a[0] += bv; a[1] += bv; a[2] += bv; a[3] += bv;
    Zt[t] = a;
  }
  // Attn = Q@K^T (16x16)
  f32x4 Atn = {0.f, 0.f, 0.f, 0.f};
#pragma unroll
  for (int s = 0; s < 2; ++s) {
    Atn = MFMA16(qH[s], kH[s], Atn);
    Atn = MFMA16(qL[s], kH[s], Atn);
    Atn = MFMA16(qH[s], kL[s], Atn);
  }

  // LN(Z) + vjp
  float gw[4], gb[4];
#pragma unroll
  for (int t = 0; t < 4; ++t) {
    gw[t] = ttt_w[h * 64 + t * 16 + fr];
    gb[t] = ttt_b[h * 64 + t * 16 + fr];
  }
  float s1[4], s2[4];
#pragma unroll
  for (int r = 0; r < 4; ++r) {
    float a0 = Zt[0][r], a1 = Zt[1][r], a2 = Zt[2][r], a3 = Zt[3][r];
    s1[r] = a0 + a1 + a2 + a3;
    s2[r] = a0 * a0 + a1 * a1 + a2 * a2 + a3 * a3;
  }
#pragma unroll
  for (int off = 1; off <= 8; off <<= 1) {
#pragma unroll
    for (int r = 0; r < 4; ++r) {
      s1[r] += __shfl_xor(s1[r], off, 64);
      s2[r] += __shfl_xor(s2[r], off, 64);
    }
  }
  float mu[4], rstd[4];
#pragma unroll
  for (int r = 0; r < 4; ++r) {
    mu[r] = s1[r] * 0.015625f;
    float var = s2[r] * 0.015625f - mu[r] * mu[r];
    rstd[r] = rsqrtf(var + 1e-5f);
  }
  float xc[4][4], gxn[4][4];
  float s3[4] = {0, 0, 0, 0}, s4[4] = {0, 0, 0, 0}, s5[4] = {0, 0, 0, 0};
#pragma unroll
  for (int t = 0; t < 4; ++t) {
#pragma unroll
    for (int r = 0; r < 4; ++r) {
      float z = Zt[t][r];
      float x = z - mu[r];
      xc[t][r] = x;
      float ln = x * rstd[r] * gw[t] + gb[t];
      float vV = Vp[(qd * 4 + r) * 64 + t * 16 + fr];
      float vK = Kp[(qd * 4 + r) * 64 + t * 16 + fr];
      float go = ln - (vV - vK);
      float gx = go * gw[t];
      gxn[t][r] = gx;
      s3[r] += gx * x;
      s4[r] += gx;
      s5[r] += x;
    }
  }
#pragma unroll
  for (int off = 1; off <= 8; off <<= 1) {
#pragma unroll
    for (int r = 0; r < 4; ++r) {
      s3[r] += __shfl_xor(s3[r], off, 64);
      s4[r] += __shfl_xor(s4[r], off, 64);
      s5[r] += __shfl_xor(s5[r], off, 64);
    }
  }
  float gvar[4], gmu[4];
#pragma unroll
  for (int r = 0; r < 4; ++r) {
    float r3 = rstd[r] * rstd[r] * rstd[r];
    gvar[r] = -0.5f * s3[r] * r3;
    gmu[r] = -s4[r] * rstd[r] + gvar[r] * (-2.0f * s5[r]) * 0.015625f;
  }
  // gZ -> LDS transposed [e][m], hi/lo bf16
#pragma unroll
  for (int t = 0; t < 4; ++t) {
    u16 hb[4], lb_[4];
#pragma unroll
    for (int r = 0; r < 4; ++r) {
      float gz = gxn[t][r] * rstd[r] + gvar[r] * 2.0f * xc[t][r] * 0.015625f + gmu[r] * 0.015625f;
      f2hl(gz, hb[r], lb_[r]);
    }
    uint2 ph, pl;
    ph.x = hb[0] | ((u32)hb[1] << 16); ph.y = hb[2] | ((u32)hb[3] << 16);
    pl.x = lb_[0] | ((u32)lb_[1] << 16); pl.y = lb_[2] | ((u32)lb_[3] << 16);
    *(uint2*)(&gzH[wv][(t * 16 + fr) * 24 + qd * 4]) = ph;
    *(uint2*)(&gzL[wv][(t * 16 + fr) * 24 + qd * 4]) = pl;
  }
  // Attn -> LDS transposed At[n][m]
  *(f32x4*)(&At[wv][fr * 20 + qd * 4]) = Atn;

  // Combined A = em[m]*(1 + tril(Attn))[m][n] for n<=m  (covers tril1 + Attn terms)
  float em = ep[fr];
  short8 aH = s8zero(), aL = s8zero();
  if (qd < 2) {
#pragma unroll
    for (int j = 0; j < 8; ++j) {
      int nn = qd * 8 + j;
      float av = 0.0f;
      if (nn <= fr) av = em * (1.0f + At[wv][nn * 20 + fr]);
      u16 hb, lb_;
      f2hl(av, hb, lb_);
      aH[j] = (short)hb;
      aL[j] = (short)lb_;
    }
  }
  // Zb = Q@W + b - Acomb@gZ
  f32x4 Ob[4];
#pragma unroll
  for (int t = 0; t < 4; ++t) {
    f32x4 a = {0.f, 0.f, 0.f, 0.f};
#pragma unroll
    for (int s = 0; s < 2; ++s) {
      short8 wH = *(const short8*)(&WtH[(t * 16 + fr) * 72 + s * 32 + qd * 8]);
      short8 wL = *(const short8*)(&WtL[(t * 16 + fr) * 72 + s * 32 + qd * 8]);
      a = MFMA16(qH[s], wH, a);
      a = MFMA16(qL[s], wH, a);
      a = MFMA16(qH[s], wL, a);
    }
    short8 gH = s8zero(), gL = s8zero();
    if (qd < 2) {
      gH = *(const short8*)(&gzH[wv][(t * 16 + fr) * 24 + qd * 8]);
      gL = *(const short8*)(&gzL[wv][(t * 16 + fr) * 24 + qd * 8]);
    }
    f32x4 c = {0.f, 0.f, 0.f, 0.f};
    c = MFMA16(aH, gH, c);
    c = MFMA16(aL, gH, c);
    c = MFMA16(aH, gL, c);
    float bv = bsh[t * 16 + fr];
#pragma unroll
    for (int r = 0; r < 4; ++r) Ob[t][r] = a[r] - c[r] + bv;
  }
  // out = Q + LN(Zb)
#pragma unroll
  for (int r = 0; r < 4; ++r) {
    float a0 = Ob[0][r], a1 = Ob[1][r], a2 = Ob[2][r], a3 = Ob[3][r];
    s1[r] = a0 + a1 + a2 + a3;
    s2[r] = a0 * a0 + a1 * a1 + a2 * a2 + a3 * a3;
  }
#pragma unroll
  for (int off = 1; off <= 8; off <<= 1) {
#pragma unroll
    for (int r = 0; r < 4; ++r) {
      s1[r] += __shfl_xor(s1[r], off, 64);
      s2[r] += __shfl_xor(s2[r], off, 64);
    }
  }
#pragma unroll
  for (int r = 0; r < 4; ++r) {
    mu[r] = s1[r] * 0.015625f;
    float var = s2[r] * 0.015625f - mu[r] * mu[r];
    rstd[r] = rsqrtf(var + 1e-5f);
  }
#pragma unroll
  for (int t = 0; t < 4; ++t) {
#pragma unroll
    for (int r = 0; r < 4; ++r) {
      float ln = (Ob[t][r] - mu[r]) * rstd[r] * gw[t] + gb[t];
      float qv = Qp[(qd * 4 + r) * 64 + t * 16 + fr];
      yout[((size_t)wv * 2048 + n * 16 + qd * 4 + r) * 1024 + h * 64 + t * 16 + fr] = qv + ln;
    }
  }
}

// ---------- kernel 4: post-LN + gate -> zb (bf16) ----------
__global__ __launch_bounds__(256) void k_postln(
    const float* __restrict__ yf, const u16* __restrict__ gateb,
    const float* __restrict__ post_w, const float* __restrict__ post_b, u16* __restrict__ zb) {
  __shared__ float red[8];
  int row = blockIdx.x, tid = threadIdx.x;
  int lane = tid & 63, wid = tid >> 6;
  const float* yr = yf + (size_t)row * 1024;
  float4 v = *(const float4*)(yr + tid * 4);
  float s1 = v.x + v.y + v.z + v.w;
  float s2 = v.x * v.x + v.y * v.y + v.z * v.z + v.w * v.w;
  s1 = wsum64(s1);
  s2 = wsum64(s2);
  if (lane == 0) { red[wid] = s1; red[4 + wid] = s2; }
  __syncthreads();
  s1 = red[0] + red[1] + red[2] + red[3];
  s2 = red[4] + red[5] + red[6] + red[7];
  float mu = s1 * (1.0f / 1024.0f);
  float var = s2 * (1.0f / 1024.0f) - mu * mu;
  float rstd = rsqrtf(var + 1e-5f);
  float vals[4] = {v.x, v.y, v.z, v.w};
  u16 ov[4];
#pragma unroll
  for (int i = 0; i < 4; ++i) {
    int cc = tid * 4 + i;
    float yn = (vals[i] - mu) * rstd * post_w[cc] + post_b[cc];
    float gt = bf2f(gateb[(size_t)row * 1024 + cc]);
    ov[i] = f2bf(gt * yn);
  }
  ushort4 o;
  o.x = ov[0]; o.y = ov[1]; o.z = ov[2]; o.w = ov[3];
  *(ushort4*)(zb + (size_t)row * 1024 + tid * 4) = o;
}

// ---------- kernel 5: output GEMM ----------
__global__ __launch_bounds__(256) void k_gemm2(const u16* __restrict__ A, const u16* __restrict__ Bw,
                                               float* __restrict__ Out) {
  __shared__ __align__(16) u16 sA[128 * 40];
  __shared__ __align__(16) u16 sB[128 * 40];
  int bm = blockIdx.x & 63, bn = blockIdx.x >> 6;
  f32x4 acc[4][4];
  gemm_core(A, Bw, bm, bn, sA, sB, acc);
  int tid = threadIdx.x, lane = tid & 63, wid = tid >> 6;
  int fr = lane & 15, qd = lane >> 4;
  int wm = (wid & 1) * 64, wn = (wid >> 1) * 64;
#pragma unroll
  for (int i = 0; i < 4; ++i) {
    int gr0 = bm * 128 + wm + i * 16 + qd * 4;
#pragma unroll
    for (int j = 0; j < 4; ++j) {
      int gc = bn * 128 + wn + j * 16 + fr;
#pragma unroll
      for (int r = 0; r < 4; ++r) Out[(size_t)(gr0 + r) * 1024 + gc] = acc[i][j][r];
    }
  }
}

// ---------- workspace layout (bytes) ----------
#define OFF_XB    ((size_t)0)          // 8192*1024 bf16      = 16777216
#define OFF_WCAT  ((size_t)16777216)   // 4224*1024 bf16      =  8650752
#define OFF_WOB   ((size_t)25427968)   // 1024*1024 bf16      =  2097152
#define OFF_Q     ((size_t)27525120)   // 4*16*2048*64 f32    = 33554432
#define OFF_K     ((size_t)61079552)
#define OFF_V     ((size_t)94633984)
#define OFF_GATE  ((size_t)128188416)  // 8192*1024 bf16
#define OFF_ETA   ((size_t)144965632)  // 4*16*2048 f32
#define OFF_WSEQ  ((size_t)145489920)  // 16*128*64*64 f32
#define OFF_BSEQ  ((size_t)179044352)  // 16*128*64 f32
#define OFF_Y     ((size_t)179568640)  // 8192*1024 f32
#define OFF_ZB    ((size_t)213123072)  // 8192*1024 bf16  (end = 229900288)

extern "C" void kernel_launch(void* const* d_in, const int* in_sizes, int n_in,
                              void* d_out, int out_size, void* d_ws, size_t ws_size,
                              hipStream_t stream) {
  const float* x    = (const float*)d_in[0];
  const float* Wq   = (const float*)d_in[1];
  const float* Wk   = (const float*)d_in[2];
  const float* Wv   = (const float*)d_in[3];
  const float* Wini = (const float*)d_in[4];
  const float* bini = (const float*)d_in[5];
  const float* ttw  = (const float*)d_in[6];
  const float* ttb  = (const float*)d_in[7];
  const float* pw   = (const float*)d_in[8];
  const float* pb   = (const float*)d_in[9];
  const float* lrw  = (const float*)d_in[10];
  const float* lrb  = (const float*)d_in[11];
  const float* tio  = (const float*)d_in[12];
  const float* Wg   = (const float*)d_in[13];
  const float* Wo   = (const float*)d_in[14];
  (void)in_sizes; (void)n_in; (void)out_size; (void)ws_size;
  float* out = (float*)d_out;
  char* ws = (char*)d_ws;
  u16* xb    = (u16*)(ws + OFF_XB);
  u16* Wcat  = (u16*)(ws + OFF_WCAT);
  u16* Wob   = (u16*)(ws + OFF_WOB);
  float* Qf  = (float*)(ws + OFF_Q);
  float* Kf  = (float*)(ws + OFF_K);
  float* Vf  = (float*)(ws + OFF_V);
  u16* gateb = (u16*)(ws + OFF_GATE);
  float* eta = (float*)(ws + OFF_ETA);
  float* Wsq = (float*)(ws + OFF_WSEQ);
  float* bsq = (float*)(ws + OFF_BSEQ);
  float* yf  = (float*)(ws + OFF_Y);
  u16* zbuf  = (u16*)(ws + OFF_ZB);

  hipLaunchKernelGGL(k_cast, dim3(13440), dim3(256), 0, stream, x, Wq, Wk, Wv, Wg, lrw, Wo, xb, Wcat, Wob);
  hipLaunchKernelGGL(k_gemm1, dim3(64 * 33), dim3(256), 0, stream, xb, Wcat, Qf, Kf, Vf, gateb, eta, lrb, tio);
  hipLaunchKernelGGL(k_phaseA, dim3(16), dim3(256), 0, stream, Kf, Vf, eta, Wini, bini, ttw, ttb, Wsq, bsq);
  hipLaunchKernelGGL(k_phaseB, dim3(2048), dim3(256), 0, stream, Qf, Kf, Vf, eta, Wsq, bsq, ttw, ttb, yf);
  hipLaunchKernelGGL(k_postln, dim3(8192), dim3(256), 0, stream, yf, gateb, pw, pb, zbuf);
  hipLaunchKernelGGL(k_gemm2, dim3(64 * 8), dim3(256), 0, stream, zbuf, Wob, out);
}

// Round 4
// 571.815 us; speedup vs baseline: 1.0642x; 1.0642x over previous
//
#include <hip/hip_runtime.h>
#include <hip/hip_bf16.h>
#include <math.h>

typedef unsigned short u16;
typedef unsigned int u32;
typedef __attribute__((ext_vector_type(8))) short short8;
typedef __attribute__((ext_vector_type(4))) float f32x4;

#define MFMA16(a,b,c) __builtin_amdgcn_mfma_f32_16x16x32_bf16((a),(b),(c),0,0,0)

// ---------- helpers ----------
__device__ __forceinline__ u16 f2bf(float f) {
  u32 u = __float_as_uint(f);
  u32 r = (u + 0x7FFFu + ((u >> 16) & 1u)) >> 16;
  return (u16)r;
}
__device__ __forceinline__ float bf2f(u16 h) { return __uint_as_float(((u32)h) << 16); }
__device__ __forceinline__ void f2hl(float f, u16& h, u16& l) {
  h = f2bf(f);
  l = f2bf(f - bf2f(h));
}
__device__ __forceinline__ float wsum64(float v) {
#pragma unroll
  for (int off = 32; off > 0; off >>= 1) v += __shfl_xor(v, off, 64);
  return v;
}
// DPP wave-64 sum: row_shr 1/2/4/8 + row_bcast15/31; total lands in lane 63,
// broadcast via readlane -> SGPR.
__device__ __forceinline__ float wred64(float v) {
  v += __int_as_float(__builtin_amdgcn_update_dpp(0, __float_as_int(v), 0x111, 0xf, 0xf, true));
  v += __int_as_float(__builtin_amdgcn_update_dpp(0, __float_as_int(v), 0x112, 0xf, 0xf, true));
  v += __int_as_float(__builtin_amdgcn_update_dpp(0, __float_as_int(v), 0x114, 0xf, 0xf, true));
  v += __int_as_float(__builtin_amdgcn_update_dpp(0, __float_as_int(v), 0x118, 0xf, 0xf, true));
  v += __int_as_float(__builtin_amdgcn_update_dpp(0, __float_as_int(v), 0x142, 0xa, 0xf, true));
  v += __int_as_float(__builtin_amdgcn_update_dpp(0, __float_as_int(v), 0x143, 0xc, 0xf, true));
  return __int_as_float(__builtin_amdgcn_readlane(__float_as_int(v), 63));
}
// broadcast lane (SGPR/uniform index) of a float register to all lanes
__device__ __forceinline__ float rdlane(float v, int lane) {
  return __int_as_float(__builtin_amdgcn_readlane(__float_as_int(v), lane));
}
__device__ __forceinline__ short8 s8zero() {
  short8 v;
#pragma unroll
  for (int j = 0; j < 8; ++j) v[j] = 0;
  return v;
}

// ---------- kernel 0: cast inputs to bf16 (xb, Wcat[4224x1024], Wob) ----------
// chunks: xb 2097152, Wcat 1081344, Wob 262144  => total 3440640 = 13440*256
__global__ __launch_bounds__(256) void k_cast(
    const float* __restrict__ x, const float* __restrict__ Wq, const float* __restrict__ Wk,
    const float* __restrict__ Wv, const float* __restrict__ Wg, const float* __restrict__ lrw,
    const float* __restrict__ Wo, u16* __restrict__ xb, u16* __restrict__ Wcat, u16* __restrict__ Wob) {
  int c = blockIdx.x * 256 + threadIdx.x;
  float4 v = make_float4(0.f, 0.f, 0.f, 0.f);
  u16* dst;
  if (c < 2097152) {
    v = *(const float4*)(x + (size_t)c * 4);
    dst = xb + (size_t)c * 4;
  } else if (c < 2097152 + 1081344) {
    int c2 = c - 2097152;
    int base = c2 * 4;
    int nr = base >> 10, col = base & 1023;
    if (nr < 1024)      v = *(const float4*)(Wq  + (size_t)nr * 1024 + col);
    else if (nr < 2048) v = *(const float4*)(Wk  + (size_t)(nr - 1024) * 1024 + col);
    else if (nr < 3072) v = *(const float4*)(Wv  + (size_t)(nr - 2048) * 1024 + col);
    else if (nr < 4096) v = *(const float4*)(Wg  + (size_t)(nr - 3072) * 1024 + col);
    else if (nr < 4112) v = *(const float4*)(lrw + (size_t)(nr - 4096) * 1024 + col);
    // rows 4112..4223 stay zero (N padding)
    dst = Wcat + (size_t)base;
  } else {
    int c2 = c - (2097152 + 1081344);
    v = *(const float4*)(Wo + (size_t)c2 * 4);
    dst = Wob + (size_t)c2 * 4;
  }
  ushort4 o;
  o.x = f2bf(v.x); o.y = f2bf(v.y); o.z = f2bf(v.z); o.w = f2bf(v.w);
  *(ushort4*)dst = o;
}

// ---------- shared GEMM core: C[8192-tile x N-tile] = A @ B^T, bf16 MFMA ----------
// A: [M][1024] bf16 row-major, Bw: [N][1024] bf16 row-major (both K-contiguous, NT GEMM)
// 128x128 tile, BK=32, 4 waves each 64x64 (4x4 of 16x16 tiles)
__device__ __forceinline__ void gemm_core(const u16* __restrict__ A, const u16* __restrict__ Bw,
                                          int bm, int bn, u16* sA, u16* sB, f32x4 acc[4][4]) {
  int tid = threadIdx.x;
  int lane = tid & 63, wid = tid >> 6;
  int fr = lane & 15, qd = lane >> 4;
  int wm = (wid & 1) * 64, wn = (wid >> 1) * 64;
#pragma unroll
  for (int i = 0; i < 4; ++i)
#pragma unroll
    for (int j = 0; j < 4; ++j) {
      f32x4 zz = {0.f, 0.f, 0.f, 0.f};
      acc[i][j] = zz;
    }
  for (int k0 = 0; k0 < 1024; k0 += 32) {
    __syncthreads();
#pragma unroll
    for (int cc = 0; cc < 2; ++cc) {
      int ch = tid + cc * 256;
      int row = ch >> 2, kp = (ch & 3) << 3;
      *(uint4*)(sA + row * 40 + kp) = *(const uint4*)(A + (size_t)(bm * 128 + row) * 1024 + k0 + kp);
      *(uint4*)(sB + row * 40 + kp) = *(const uint4*)(Bw + (size_t)(bn * 128 + row) * 1024 + k0 + kp);
    }
    __syncthreads();
    short8 af[4], bfr[4];
#pragma unroll
    for (int i = 0; i < 4; ++i) af[i] = *(const short8*)(sA + (wm + i * 16 + fr) * 40 + qd * 8);
#pragma unroll
    for (int j = 0; j < 4; ++j) bfr[j] = *(const short8*)(sB + (wn + j * 16 + fr) * 40 + qd * 8);
#pragma unroll
    for (int i = 0; i < 4; ++i)
#pragma unroll
      for (int j = 0; j < 4; ++j) acc[i][j] = MFMA16(af[i], bfr[j], acc[i][j]);
  }
}

// ---------- kernel 1: fused QKV + gate + lr projection ----------
__global__ __launch_bounds__(256) void k_gemm1(
    const u16* __restrict__ A, const u16* __restrict__ Bw,
    float* __restrict__ Qf, float* __restrict__ Kf, float* __restrict__ Vf,
    u16* __restrict__ gateb, float* __restrict__ eta,
    const float* __restrict__ lr_b, const float* __restrict__ tio) {
  __shared__ __align__(16) u16 sA[128 * 40];
  __shared__ __align__(16) u16 sB[128 * 40];
  int bm = blockIdx.x & 63, bn = blockIdx.x >> 6;
  f32x4 acc[4][4];
  gemm_core(A, Bw, bm, bn, sA, sB, acc);
  int tid = threadIdx.x, lane = tid & 63, wid = tid >> 6;
  int fr = lane & 15, qd = lane >> 4;
  int wm = (wid & 1) * 64, wn = (wid >> 1) * 64;
#pragma unroll
  for (int i = 0; i < 4; ++i) {
    int gr0 = bm * 128 + wm + i * 16 + qd * 4;
#pragma unroll
    for (int j = 0; j < 4; ++j) {
      int gc = bn * 128 + wn + j * 16 + fr;
      if (gc < 3072) {
        int p = gc >> 10, rem = gc & 1023, hd = rem >> 6, dd = rem & 63;
        float* dst = (p == 0) ? Qf : ((p == 1) ? Kf : Vf);
#pragma unroll
        for (int r = 0; r < 4; ++r) {
          int gr = gr0 + r;
          int b_ = gr >> 11, s = gr & 2047;
          dst[(((size_t)(b_ * 16 + hd)) * 2048 + s) * 64 + dd] = acc[i][j][r];
        }
      } else if (gc < 4096) {
        int j2 = gc - 3072;
#pragma unroll
        for (int r = 0; r < 4; ++r) {
          int gr = gr0 + r;
          float vv = acc[i][j][r];
          float gl = 0.5f * vv * (1.0f + erff(vv * 0.70710678118654752f));  // exact gelu
          gateb[(size_t)gr * 1024 + j2] = f2bf(gl);
        }
      } else if (gc < 4112) {
        int hd = gc - 4096;
        float lb = lr_b[hd];
#pragma unroll
        for (int r = 0; r < 4; ++r) {
          int gr = gr0 + r;
          int b_ = gr >> 11, s = gr & 2047, m = s & 15;
          float lm = 1.0f / (1.0f + expf(-(acc[i][j][r] + lb)));
          float tok = fmaxf(1.0f / (float)(m + 1) + tio[m], 0.0f);
          eta[((size_t)(b_ * 16 + hd)) * 2048 + s] = tok * lm * 0.015625f;  // /D
        }
      }
    }
  }
}

// ---------- kernel 2: Phase A — sequential W/b trajectory per head ----------
// R4: kill the SMEM k-slice reads (SGPR ceiling forced serialized s_load
// batches -> ~5000 cyc/step). K rows stay lane-resident (2-deep register
// prefetch); matvec & W-update broadcast k values with v_readlane (SGPR-
// indexed, wave-uniform) — no memory on the critical path.
__global__ __launch_bounds__(256) void k_phaseA(
    const float* __restrict__ Kf, const float* __restrict__ Vf, const float* __restrict__ eta,
    const float* __restrict__ W_init, const float* __restrict__ b_init,
    const float* __restrict__ ttt_w, const float* __restrict__ ttt_b,
    float* __restrict__ Wseq, float* __restrict__ bseq) {
  __shared__ float pbuf[2][4][4][64];  // [buf][d-slice wave][batch][e]
  __shared__ float ush[2][4][64];      // [buf][batch][e]
  int h = blockIdx.x;
  int tid = threadIdx.x, lane = tid & 63;
  int wu = __builtin_amdgcn_readfirstlane(tid >> 6);  // wave-uniform wave id
  int wu16 = wu * 16;
  float Wreg[16];
#pragma unroll
  for (int i = 0; i < 16; ++i) Wreg[i] = W_init[(size_t)h * 4096 + (wu16 + i) * 64 + lane];
  float bcur = b_init[h * 64 + lane];
  float g = ttt_w[h * 64 + lane], tb = ttt_b[h * 64 + lane];
  // last-row bases (batch 0..3); row n at float offset n*1024
  const float* kb0 = Kf + (((size_t)(0 * 16 + h)) * 2048 + 15) * 64;
  const float* kb1 = Kf + (((size_t)(1 * 16 + h)) * 2048 + 15) * 64;
  const float* kb2 = Kf + (((size_t)(2 * 16 + h)) * 2048 + 15) * 64;
  const float* kb3 = Kf + (((size_t)(3 * 16 + h)) * 2048 + 15) * 64;
  const float* vbw = Vf + (((size_t)(wu * 16 + h)) * 2048 + 15) * 64;
  const float* erow = eta + ((size_t)(wu * 16 + h)) * 2048 + 15;  // erow[n*16]

  // ---- prologue: rows 0 and 1 lane-resident; z^0 = K^0 W_0 + b_0 ----
  float kc0 = kb0[lane], kc1 = kb1[lane], kc2 = kb2[lane], kc3 = kb3[lane];
  float kn0 = kb0[1024 + lane], kn1 = kb1[1024 + lane];
  float kn2 = kb2[1024 + lane], kn3 = kb3[1024 + lane];
  float vcur = vbw[lane], vnx = vbw[1024 + lane];
  float ecur = erow[0], enx = erow[16];
  {
    float p0 = 0.f, p1 = 0.f, p2 = 0.f, p3 = 0.f;
#pragma unroll
    for (int i = 0; i < 16; ++i) {
      float wr = Wreg[i];
      p0 += rdlane(kc0, wu16 + i) * wr;
      p1 += rdlane(kc1, wu16 + i) * wr;
      p2 += rdlane(kc2, wu16 + i) * wr;
      p3 += rdlane(kc3, wu16 + i) * wr;
    }
    pbuf[0][wu][0][lane] = p0; pbuf[0][wu][1][lane] = p1;
    pbuf[0][wu][2][lane] = p2; pbuf[0][wu][3][lane] = p3;
  }
  __syncthreads();
  float zc = pbuf[0][0][wu][lane] + pbuf[0][1][wu][lane] +
             pbuf[0][2][wu][lane] + pbuf[0][3][wu][lane] + bcur;

  for (int n = 0; n < 128; ++n) {
    int bi = n & 1, pi = (n + 1) & 1;
    int nf = (n < 126) ? n + 2 : 127;  // 2-ahead prefetch row
    size_t nfoff = (size_t)nf * 1024;
    // A. issue 2-ahead prefetch (lands by iter n+1)
    float kf0 = kb0[nfoff + lane], kf1 = kb1[nfoff + lane];
    float kf2 = kb2[nfoff + lane], kf3 = kb3[nfoff + lane];
    float vfx = vbw[nfoff + lane];
    float efx = erow[nf * 16];
    // B. snapshot W_n / b_n (drain overlaps this step's work)
    {
      float* wdst = Wseq + (((size_t)h * 128 + n) * 64 + lane) * 64 + wu16;
#pragma unroll
      for (int i = 0; i < 16; i += 4) {
        float4 t4;
        t4.x = Wreg[i]; t4.y = Wreg[i + 1]; t4.z = Wreg[i + 2]; t4.w = Wreg[i + 3];
        *(float4*)(wdst + i) = t4;
      }
      if (wu == 0) bseq[((size_t)h * 128 + n) * 64 + lane] = bcur;
    }
    // C. partials K^{n+1} . W_n via readlane broadcast (kn landed last iter)
    {
      float p0 = 0.f, p1 = 0.f, p2 = 0.f, p3 = 0.f;
#pragma unroll
      for (int i = 0; i < 16; ++i) {
        float wr = Wreg[i];
        p0 += rdlane(kn0, wu16 + i) * wr;
        p1 += rdlane(kn1, wu16 + i) * wr;
        p2 += rdlane(kn2, wu16 + i) * wr;
        p3 += rdlane(kn3, wu16 + i) * wr;
      }
      pbuf[pi][wu][0][lane] = p0; pbuf[pi][wu][1][lane] = p1;
      pbuf[pi][wu][2][lane] = p2; pbuf[pi][wu][3][lane] = p3;
    }
    // D. D-dots: own next-row against all current rows
    float kon = (wu == 0) ? kn0 : (wu == 1) ? kn1 : (wu == 2) ? kn2 : kn3;
    float D0 = wred64(kon * kc0), D1 = wred64(kon * kc1);
    float D2 = wred64(kon * kc2), D3 = wred64(kon * kc3);
    // E. LN-vjp on z^n (wave wu handles batch wu's last row)
    float kl = (wu == 0) ? kc0 : (wu == 1) ? kc1 : (wu == 2) ? kc2 : kc3;
    float s1 = wred64(zc), s2 = wred64(zc * zc);
    float mu = s1 * 0.015625f;
    float var = s2 * 0.015625f - mu * mu;
    float rstd = rsqrtf(var + 1e-5f);
    float xc = zc - mu;
    float ln = xc * rstd * g + tb;
    float go = ln - (vcur - kl);
    float gxn = go * g;
    float sa = wred64(gxn * xc), sb_ = wred64(gxn);
    float gvar = -0.5f * sa * rstd * rstd * rstd;
    float gmu = -sb_ * rstd;  // sum(xc) term ~0, dropped
    float gz = gxn * rstd + gvar * 2.0f * xc * 0.015625f + gmu * 0.015625f;
    ush[bi][wu][lane] = ecur * gz;
    __syncthreads();
    // F. u exchange; b update; z^{n+1} assembly
    float u0 = ush[bi][0][lane], u1 = ush[bi][1][lane];
    float u2 = ush[bi][2][lane], u3 = ush[bi][3][lane];
    float bnext = bcur - 0.25f * (u0 + u1 + u2 + u3);
    float zsum = pbuf[pi][0][wu][lane] + pbuf[pi][1][wu][lane] +
                 pbuf[pi][2][wu][lane] + pbuf[pi][3][wu][lane];
    zc = zsum - 0.25f * (D0 * u0 + D1 * u1 + D2 * u2 + D3 * u3) + bnext;
    // G. W update with k^n via readlane broadcast
#pragma unroll
    for (int i = 0; i < 16; ++i) {
      float a = rdlane(kc0, wu16 + i) * u0 + rdlane(kc1, wu16 + i) * u1 +
                rdlane(kc2, wu16 + i) * u2 + rdlane(kc3, wu16 + i) * u3;
      Wreg[i] -= 0.25f * a;
    }
    // H. rotate prefetch registers
    kc0 = kn0; kc1 = kn1; kc2 = kn2; kc3 = kn3;
    kn0 = kf0; kn1 = kf1; kn2 = kf2; kn3 = kf3;
    vcur = vnx; vnx = vfx; ecur = enx; enx = efx; bcur = bnext;
  }
}

// ---------- kernel 3: Phase B — per-(minibatch, head) full outputs via MFMA hi/lo ----------
__global__ __launch_bounds__(256) void k_phaseB(
    const float* __restrict__ Qf, const float* __restrict__ Kf, const float* __restrict__ Vf,
    const float* __restrict__ eta, const float* __restrict__ Wseq, const float* __restrict__ bseq,
    const float* __restrict__ ttt_w, const float* __restrict__ ttt_b, float* __restrict__ yout) {
  __shared__ __align__(16) u16 WtH[64 * 72], WtL[64 * 72];   // W^T [e][d] hi/lo bf16, pad 72
  __shared__ __align__(16) u16 gzH[4][64 * 24], gzL[4][64 * 24];  // gZ^T [e][m] per wave
  __shared__ __align__(16) float At[4][16 * 20];             // Attn^T [n][m] per wave
  __shared__ float bsh[64];
  int bx = blockIdx.x;
  int n = bx & 127, h = bx >> 7;
  int tid = threadIdx.x, lane = tid & 63, wv = tid >> 6;  // wave = batch
  int fr = lane & 15, qd = lane >> 4;

  // stage W_n (already [e][d]) -> hi/lo bf16 LDS
  {
    int e = tid >> 2, d0 = (tid & 3) << 4;
    const float* src = Wseq + (((size_t)h * 128 + n) * 64 + e) * 64 + d0;
#pragma unroll
    for (int gsub = 0; gsub < 2; ++gsub) {
      u16 hb[8], lb_[8];
#pragma unroll
      for (int i = 0; i < 8; i += 4) {
        float4 v = *(const float4*)(src + gsub * 8 + i);
        f2hl(v.x, hb[i], lb_[i]);
        f2hl(v.y, hb[i + 1], lb_[i + 1]);
        f2hl(v.z, hb[i + 2], lb_[i + 2]);
        f2hl(v.w, hb[i + 3], lb_[i + 3]);
      }
      uint4 ph, pl;
      ph.x = hb[0] | ((u32)hb[1] << 16); ph.y = hb[2] | ((u32)hb[3] << 16);
      ph.z = hb[4] | ((u32)hb[5] << 16); ph.w = hb[6] | ((u32)hb[7] << 16);
      pl.x = lb_[0] | ((u32)lb_[1] << 16); pl.y = lb_[2] | ((u32)lb_[3] << 16);
      pl.z = lb_[4] | ((u32)lb_[5] << 16); pl.w = lb_[6] | ((u32)lb_[7] << 16);
      *(uint4*)(&WtH[e * 72 + d0 + gsub * 8]) = ph;
      *(uint4*)(&WtL[e * 72 + d0 + gsub * 8]) = pl;
    }
    if (tid < 64) bsh[tid] = bseq[((size_t)h * 128 + n) * 64 + tid];
  }
  __syncthreads();

  const size_t bh = (size_t)(wv * 16 + h);
  const float* Qp = Qf + (bh * 2048 + (size_t)n * 16) * 64;
  const float* Kp = Kf + (bh * 2048 + (size_t)n * 16) * 64;
  const float* Vp = Vf + (bh * 2048 + (size_t)n * 16) * 64;
  const float* ep = eta + bh * 2048 + n * 16;

  // Q/K A-operand fragments (also reused as B for Attn): [m=fr][k = s*32 + qd*8 + j]
  short8 qH[2], qL[2], kH[2], kL[2];
#pragma unroll
  for (int s = 0; s < 2; ++s) {
    const float* p1 = Qp + fr * 64 + s * 32 + qd * 8;
    const float* p2 = Kp + fr * 64 + s * 32 + qd * 8;
#pragma unroll
    for (int j = 0; j < 8; ++j) {
      u16 hb, lb_;
      f2hl(p1[j], hb, lb_); qH[s][j] = (short)hb; qL[s][j] = (short)lb_;
      f2hl(p2[j], hb, lb_); kH[s][j] = (short)hb; kL[s][j] = (short)lb_;
    }
  }

  // Z = K@W + b  (C-layout: row m = qd*4+r, col e = t*16+fr)
  f32x4 Zt[4];
#pragma unroll
  for (int t = 0; t < 4; ++t) {
    f32x4 a = {0.f, 0.f, 0.f, 0.f};
#pragma unroll
    for (int s = 0; s < 2; ++s) {
      short8 wH = *(const short8*)(&WtH[(t * 16 + fr) * 72 + s * 32 + qd * 8]);
      short8 wL = *(const short8*)(&WtL[(t * 16 + fr) * 72 + s * 32 + qd * 8]);
      a = MFMA16(kH[s], wH, a);
      a = MFMA16(kL[s], wH, a);
      a = MFMA16(kH[s], wL, a);
    }
    float bv = bsh[t * 16 + fr];
    a[0] += bv; a[1] += bv; a[2] += bv; a[3] += bv;
    Zt[t] = a;
  }
  // Attn = Q@K^T (16x16)
  f32x4 Atn = {0.f, 0.f, 0.f, 0.f};
#pragma unroll
  for (int s = 0; s < 2; ++s) {
    Atn = MFMA16(qH[s], kH[s], Atn);
    Atn = MFMA16(qL[s], kH[s], Atn);
    Atn = MFMA16(qH[s], kL[s], Atn);
  }

  // LN(Z) + vjp
  float gw[4], gb[4];
#pragma unroll
  for (int t = 0; t < 4; ++t) {
    gw[t] = ttt_w[h * 64 + t * 16 + fr];
    gb[t] = ttt_b[h * 64 + t * 16 + fr];
  }
  float s1[4], s2[4];
#pragma unroll
  for (int r = 0; r < 4; ++r) {
    float a0 = Zt[0][r], a1 = Zt[1][r], a2 = Zt[2][r], a3 = Zt[3][r];
    s1[r] = a0 + a1 + a2 + a3;
    s2[r] = a0 * a0 + a1 * a1 + a2 * a2 + a3 * a3;
  }
#pragma unroll
  for (int off = 1; off <= 8; off <<= 1) {
#pragma unroll
    for (int r = 0; r < 4; ++r) {
      s1[r] += __shfl_xor(s1[r], off, 64);
      s2[r] += __shfl_xor(s2[r], off, 64);
    }
  }
  float mu[4], rstd[4];
#pragma unroll
  for (int r = 0; r < 4; ++r) {
    mu[r] = s1[r] * 0.015625f;
    float var = s2[r] * 0.015625f - mu[r] * mu[r];
    rstd[r] = rsqrtf(var + 1e-5f);
  }
  float xc[4][4], gxn[4][4];
  float s3[4] = {0, 0, 0, 0}, s4[4] = {0, 0, 0, 0}, s5[4] = {0, 0, 0, 0};
#pragma unroll
  for (int t = 0; t < 4; ++t) {
#pragma unroll
    for (int r = 0; r < 4; ++r) {
      float z = Zt[t][r];
      float x = z - mu[r];
      xc[t][r] = x;
      float ln = x * rstd[r] * gw[t] + gb[t];
      float vV = Vp[(qd * 4 + r) * 64 + t * 16 + fr];
      float vK = Kp[(qd * 4 + r) * 64 + t * 16 + fr];
      float go = ln - (vV - vK);
      float gx = go * gw[t];
      gxn[t][r] = gx;
      s3[r] += gx * x;
      s4[r] += gx;
      s5[r] += x;
    }
  }
#pragma unroll
  for (int off = 1; off <= 8; off <<= 1) {
#pragma unroll
    for (int r = 0; r < 4; ++r) {
      s3[r] += __shfl_xor(s3[r], off, 64);
      s4[r] += __shfl_xor(s4[r], off, 64);
      s5[r] += __shfl_xor(s5[r], off, 64);
    }
  }
  float gvar[4], gmu[4];
#pragma unroll
  for (int r = 0; r < 4; ++r) {
    float r3 = rstd[r] * rstd[r] * rstd[r];
    gvar[r] = -0.5f * s3[r] * r3;
    gmu[r] = -s4[r] * rstd[r] + gvar[r] * (-2.0f * s5[r]) * 0.015625f;
  }
  // gZ -> LDS transposed [e][m], hi/lo bf16
#pragma unroll
  for (int t = 0; t < 4; ++t) {
    u16 hb[4], lb_[4];
#pragma unroll
    for (int r = 0; r < 4; ++r) {
      float gz = gxn[t][r] * rstd[r] + gvar[r] * 2.0f * xc[t][r] * 0.015625f + gmu[r] * 0.015625f;
      f2hl(gz, hb[r], lb_[r]);
    }
    uint2 ph, pl;
    ph.x = hb[0] | ((u32)hb[1] << 16); ph.y = hb[2] | ((u32)hb[3] << 16);
    pl.x = lb_[0] | ((u32)lb_[1] << 16); pl.y = lb_[2] | ((u32)lb_[3] << 16);
    *(uint2*)(&gzH[wv][(t * 16 + fr) * 24 + qd * 4]) = ph;
    *(uint2*)(&gzL[wv][(t * 16 + fr) * 24 + qd * 4]) = pl;
  }
  // Attn -> LDS transposed At[n][m]
  *(f32x4*)(&At[wv][fr * 20 + qd * 4]) = Atn;

  // Combined A = em[m]*(1 + tril(Attn))[m][n] for n<=m  (covers tril1 + Attn terms)
  float em = ep[fr];
  short8 aH = s8zero(), aL = s8zero();
  if (qd < 2) {
#pragma unroll
    for (int j = 0; j < 8; ++j) {
      int nn = qd * 8 + j;
      float av = 0.0f;
      if (nn <= fr) av = em * (1.0f + At[wv][nn * 20 + fr]);
      u16 hb, lb_;
      f2hl(av, hb, lb_);
      aH[j] = (short)hb;
      aL[j] = (short)lb_;
    }
  }
  // Zb = Q@W + b - Acomb@gZ
  f32x4 Ob[4];
#pragma unroll
  for (int t = 0; t < 4; ++t) {
    f32x4 a = {0.f, 0.f, 0.f, 0.f};
#pragma unroll
    for (int s = 0; s < 2; ++s) {
      short8 wH = *(const short8*)(&WtH[(t * 16 + fr) * 72 + s * 32 + qd * 8]);
      short8 wL = *(const short8*)(&WtL[(t * 16 + fr) * 72 + s * 32 + qd * 8]);
      a = MFMA16(qH[s], wH, a);
      a = MFMA16(qL[s], wH, a);
      a = MFMA16(qH[s], wL, a);
    }
    short8 gH = s8zero(), gL = s8zero();
    if (qd < 2) {
      gH = *(const short8*)(&gzH[wv][(t * 16 + fr) * 24 + qd * 8]);
      gL = *(const short8*)(&gzL[wv][(t * 16 + fr) * 24 + qd * 8]);
    }
    f32x4 c = {0.f, 0.f, 0.f, 0.f};
    c = MFMA16(aH, gH, c);
    c = MFMA16(aL, gH, c);
    c = MFMA16(aH, gL, c);
    float bv = bsh[t * 16 + fr];
#pragma unroll
    for (int r = 0; r < 4; ++r) Ob[t][r] = a[r] - c[r] + bv;
  }
  // out = Q + LN(Zb)
#pragma unroll
  for (int r = 0; r < 4; ++r) {
    float a0 = Ob[0][r], a1 = Ob[1][r], a2 = Ob[2][r], a3 = Ob[3][r];
    s1[r] = a0 + a1 + a2 + a3;
    s2[r] = a0 * a0 + a1 * a1 + a2 * a2 + a3 * a3;
  }
#pragma unroll
  for (int off = 1; off <= 8; off <<= 1) {
#pragma unroll
    for (int r = 0; r < 4; ++r) {
      s1[r] += __shfl_xor(s1[r], off, 64);
      s2[r] += __shfl_xor(s2[r], off, 64);
    }
  }
#pragma unroll
  for (int r = 0; r < 4; ++r) {
    mu[r] = s1[r] * 0.015625f;
    float var = s2[r] * 0.015625f - mu[r] * mu[r];
    rstd[r] = rsqrtf(var + 1e-5f);
  }
#pragma unroll
  for (int t = 0; t < 4; ++t) {
#pragma unroll
    for (int r = 0; r < 4; ++r) {
      float ln = (Ob[t][r] - mu[r]) * rstd[r] * gw[t] + gb[t];
      float qv = Qp[(qd * 4 + r) * 64 + t * 16 + fr];
      yout[((size_t)wv * 2048 + n * 16 + qd * 4 + r) * 1024 + h * 64 + t * 16 + fr] = qv + ln;
    }
  }
}

// ---------- kernel 4: post-LN + gate -> zb (bf16) ----------
__global__ __launch_bounds__(256) void k_postln(
    const float* __restrict__ yf, const u16* __restrict__ gateb,
    const float* __restrict__ post_w, const float* __restrict__ post_b, u16* __restrict__ zb) {
  __shared__ float red[8];
  int row = blockIdx.x, tid = threadIdx.x;
  int lane = tid & 63, wid = tid >> 6;
  const float* yr = yf + (size_t)row * 1024;
  float4 v = *(const float4*)(yr + tid * 4);
  float s1 = v.x + v.y + v.z + v.w;
  float s2 = v.x * v.x + v.y * v.y + v.z * v.z + v.w * v.w;
  s1 = wsum64(s1);
  s2 = wsum64(s2);
  if (lane == 0) { red[wid] = s1; red[4 + wid] = s2; }
  __syncthreads();
  s1 = red[0] + red[1] + red[2] + red[3];
  s2 = red[4] + red[5] + red[6] + red[7];
  float mu = s1 * (1.0f / 1024.0f);
  float var = s2 * (1.0f / 1024.0f) - mu * mu;
  float rstd = rsqrtf(var + 1e-5f);
  float vals[4] = {v.x, v.y, v.z, v.w};
  u16 ov[4];
#pragma unroll
  for (int i = 0; i < 4; ++i) {
    int cc = tid * 4 + i;
    float yn = (vals[i] - mu) * rstd * post_w[cc] + post_b[cc];
    float gt = bf2f(gateb[(size_t)row * 1024 + cc]);
    ov[i] = f2bf(gt * yn);
  }
  ushort4 o;
  o.x = ov[0]; o.y = ov[1]; o.z = ov[2]; o.w = ov[3];
  *(ushort4*)(zb + (size_t)row * 1024 + tid * 4) = o;
}

// ---------- kernel 5: output GEMM ----------
__global__ __launch_bounds__(256) void k_gemm2(const u16* __restrict__ A, const u16* __restrict__ Bw,
                                               float* __restrict__ Out) {
  __shared__ __align__(16) u16 sA[128 * 40];
  __shared__ __align__(16) u16 sB[128 * 40];
  int bm = blockIdx.x & 63, bn = blockIdx.x >> 6;
  f32x4 acc[4][4];
  gemm_core(A, Bw, bm, bn, sA, sB, acc);
  int tid = threadIdx.x, lane = tid & 63, wid = tid >> 6;
  int fr = lane & 15, qd = lane >> 4;
  int wm = (wid & 1) * 64, wn = (wid >> 1) * 64;
#pragma unroll
  for (int i = 0; i < 4; ++i) {
    int gr0 = bm * 128 + wm + i * 16 + qd * 4;
#pragma unroll
    for (int j = 0; j < 4; ++j) {
      int gc = bn * 128 + wn + j * 16 + fr;
#pragma unroll
      for (int r = 0; r < 4; ++r) Out[(size_t)(gr0 + r) * 1024 + gc] = acc[i][j][r];
    }
  }
}

// ---------- workspace layout (bytes) ----------
#define OFF_XB    ((size_t)0)          // 8192*1024 bf16      = 16777216
#define OFF_WCAT  ((size_t)16777216)   // 4224*1024 bf16      =  8650752
#define OFF_WOB   ((size_t)25427968)   // 1024*1024 bf16      =  2097152
#define OFF_Q     ((size_t)27525120)   // 4*16*2048*64 f32    = 33554432
#define OFF_K     ((size_t)61079552)
#define OFF_V     ((size_t)94633984)
#define OFF_GATE  ((size_t)128188416)  // 8192*1024 bf16
#define OFF_ETA   ((size_t)144965632)  // 4*16*2048 f32
#define OFF_WSEQ  ((size_t)145489920)  // 16*128*64*64 f32
#define OFF_BSEQ  ((size_t)179044352)  // 16*128*64 f32
#define OFF_Y     ((size_t)179568640)  // 8192*1024 f32
#define OFF_ZB    ((size_t)213123072)  // 8192*1024 bf16  (end = 229900288)

extern "C" void kernel_launch(void* const* d_in, const int* in_sizes, int n_in,
                              void* d_out, int out_size, void* d_ws, size_t ws_size,
                              hipStream_t stream) {
  const float* x    = (const float*)d_in[0];
  const float* Wq   = (const float*)d_in[1];
  const float* Wk   = (const float*)d_in[2];
  const float* Wv   = (const float*)d_in[3];
  const float* Wini = (const float*)d_in[4];
  const float* bini = (const float*)d_in[5];
  const float* ttw  = (const float*)d_in[6];
  const float* ttb  = (const float*)d_in[7];
  const float* pw   = (const float*)d_in[8];
  const float* pb   = (const float*)d_in[9];
  const float* lrw  = (const float*)d_in[10];
  const float* lrb  = (const float*)d_in[11];
  const float* tio  = (const float*)d_in[12];
  const float* Wg   = (const float*)d_in[13];
  const float* Wo   = (const float*)d_in[14];
  (void)in_sizes; (void)n_in; (void)out_size; (void)ws_size;
  float* out = (float*)d_out;
  char* ws = (char*)d_ws;
  u16* xb    = (u16*)(ws + OFF_XB);
  u16* Wcat  = (u16*)(ws + OFF_WCAT);
  u16* Wob   = (u16*)(ws + OFF_WOB);
  float* Qf  = (float*)(ws + OFF_Q);
  float* Kf  = (float*)(ws + OFF_K);
  float* Vf  = (float*)(ws + OFF_V);
  u16* gateb = (u16*)(ws + OFF_GATE);
  float* eta = (float*)(ws + OFF_ETA);
  float* Wsq = (float*)(ws + OFF_WSEQ);
  float* bsq = (float*)(ws + OFF_BSEQ);
  float* yf  = (float*)(ws + OFF_Y);
  u16* zbuf  = (u16*)(ws + OFF_ZB);

  hipLaunchKernelGGL(k_cast, dim3(13440), dim3(256), 0, stream, x, Wq, Wk, Wv, Wg, lrw, Wo, xb, Wcat, Wob);
  hipLaunchKernelGGL(k_gemm1, dim3(64 * 33), dim3(256), 0, stream, xb, Wcat, Qf, Kf, Vf, gateb, eta, lrb, tio);
  hipLaunchKernelGGL(k_phaseA, dim3(16), dim3(256), 0, stream, Kf, Vf, eta, Wini, bini, ttw, ttb, Wsq, bsq);
  hipLaunchKernelGGL(k_phaseB, dim3(2048), dim3(256), 0, stream, Qf, Kf, Vf, eta, Wsq, bsq, ttw, ttb, yf);
  hipLaunchKernelGGL(k_postln, dim3(8192), dim3(256), 0, stream, yf, gateb, pw, pb, zbuf);
  hipLaunchKernelGGL(k_gemm2, dim3(64 * 8), dim3(256), 0, stream, zbuf, Wob, out);
}

// Round 5
// 494.781 us; speedup vs baseline: 1.2299x; 1.1557x over previous
//
#include <hip/hip_runtime.h>
#include <hip/hip_bf16.h>
#include <math.h>

typedef unsigned short u16;
typedef unsigned int u32;
typedef __attribute__((ext_vector_type(8))) short short8;
typedef __attribute__((ext_vector_type(4))) float f32x4;

#define MFMA16(a,b,c) __builtin_amdgcn_mfma_f32_16x16x32_bf16((a),(b),(c),0,0,0)

// ---------- helpers ----------
__device__ __forceinline__ u16 f2bf(float f) {
  u32 u = __float_as_uint(f);
  u32 r = (u + 0x7FFFu + ((u >> 16) & 1u)) >> 16;
  return (u16)r;
}
__device__ __forceinline__ float bf2f(u16 h) { return __uint_as_float(((u32)h) << 16); }
__device__ __forceinline__ void f2hl(float f, u16& h, u16& l) {
  h = f2bf(f);
  l = f2bf(f - bf2f(h));
}
__device__ __forceinline__ float wsum64(float v) {
#pragma unroll
  for (int off = 32; off > 0; off >>= 1) v += __shfl_xor(v, off, 64);
  return v;
}
// DPP wave-64 sum: row_shr 1/2/4/8 + row_bcast15/31; total lands in lane 63,
// broadcast via readlane -> SGPR.
__device__ __forceinline__ float wred64(float v) {
  v += __int_as_float(__builtin_amdgcn_update_dpp(0, __float_as_int(v), 0x111, 0xf, 0xf, true));
  v += __int_as_float(__builtin_amdgcn_update_dpp(0, __float_as_int(v), 0x112, 0xf, 0xf, true));
  v += __int_as_float(__builtin_amdgcn_update_dpp(0, __float_as_int(v), 0x114, 0xf, 0xf, true));
  v += __int_as_float(__builtin_amdgcn_update_dpp(0, __float_as_int(v), 0x118, 0xf, 0xf, true));
  v += __int_as_float(__builtin_amdgcn_update_dpp(0, __float_as_int(v), 0x142, 0xa, 0xf, true));
  v += __int_as_float(__builtin_amdgcn_update_dpp(0, __float_as_int(v), 0x143, 0xc, 0xf, true));
  return __int_as_float(__builtin_amdgcn_readlane(__float_as_int(v), 63));
}
// broadcast lane (SGPR/uniform index) of a float register to all lanes
__device__ __forceinline__ float rdlane(float v, int lane) {
  return __int_as_float(__builtin_amdgcn_readlane(__float_as_int(v), lane));
}
__device__ __forceinline__ short8 s8zero() {
  short8 v;
#pragma unroll
  for (int j = 0; j < 8; ++j) v[j] = 0;
  return v;
}

// ---------- kernel 0: cast inputs to bf16 (xb, Wcat[4224x1024], Wob) ----------
// chunks: xb 2097152, Wcat 1081344, Wob 262144  => total 3440640 = 13440*256
__global__ __launch_bounds__(256) void k_cast(
    const float* __restrict__ x, const float* __restrict__ Wq, const float* __restrict__ Wk,
    const float* __restrict__ Wv, const float* __restrict__ Wg, const float* __restrict__ lrw,
    const float* __restrict__ Wo, u16* __restrict__ xb, u16* __restrict__ Wcat, u16* __restrict__ Wob) {
  int c = blockIdx.x * 256 + threadIdx.x;
  float4 v = make_float4(0.f, 0.f, 0.f, 0.f);
  u16* dst;
  if (c < 2097152) {
    v = *(const float4*)(x + (size_t)c * 4);
    dst = xb + (size_t)c * 4;
  } else if (c < 2097152 + 1081344) {
    int c2 = c - 2097152;
    int base = c2 * 4;
    int nr = base >> 10, col = base & 1023;
    if (nr < 1024)      v = *(const float4*)(Wq  + (size_t)nr * 1024 + col);
    else if (nr < 2048) v = *(const float4*)(Wk  + (size_t)(nr - 1024) * 1024 + col);
    else if (nr < 3072) v = *(const float4*)(Wv  + (size_t)(nr - 2048) * 1024 + col);
    else if (nr < 4096) v = *(const float4*)(Wg  + (size_t)(nr - 3072) * 1024 + col);
    else if (nr < 4112) v = *(const float4*)(lrw + (size_t)(nr - 4096) * 1024 + col);
    // rows 4112..4223 stay zero (N padding)
    dst = Wcat + (size_t)base;
  } else {
    int c2 = c - (2097152 + 1081344);
    v = *(const float4*)(Wo + (size_t)c2 * 4);
    dst = Wob + (size_t)c2 * 4;
  }
  ushort4 o;
  o.x = f2bf(v.x); o.y = f2bf(v.y); o.z = f2bf(v.z); o.w = f2bf(v.w);
  *(ushort4*)dst = o;
}

// ---------- shared GEMM core: C[8192-tile x N-tile] = A @ B^T, bf16 MFMA ----------
// A: [M][1024] bf16 row-major, Bw: [N][1024] bf16 row-major (both K-contiguous, NT GEMM)
// 128x128 tile, BK=32, 4 waves each 64x64 (4x4 of 16x16 tiles)
__device__ __forceinline__ void gemm_core(const u16* __restrict__ A, const u16* __restrict__ Bw,
                                          int bm, int bn, u16* sA, u16* sB, f32x4 acc[4][4]) {
  int tid = threadIdx.x;
  int lane = tid & 63, wid = tid >> 6;
  int fr = lane & 15, qd = lane >> 4;
  int wm = (wid & 1) * 64, wn = (wid >> 1) * 64;
#pragma unroll
  for (int i = 0; i < 4; ++i)
#pragma unroll
    for (int j = 0; j < 4; ++j) {
      f32x4 zz = {0.f, 0.f, 0.f, 0.f};
      acc[i][j] = zz;
    }
  for (int k0 = 0; k0 < 1024; k0 += 32) {
    __syncthreads();
#pragma unroll
    for (int cc = 0; cc < 2; ++cc) {
      int ch = tid + cc * 256;
      int row = ch >> 2, kp = (ch & 3) << 3;
      *(uint4*)(sA + row * 40 + kp) = *(const uint4*)(A + (size_t)(bm * 128 + row) * 1024 + k0 + kp);
      *(uint4*)(sB + row * 40 + kp) = *(const uint4*)(Bw + (size_t)(bn * 128 + row) * 1024 + k0 + kp);
    }
    __syncthreads();
    short8 af[4], bfr[4];
#pragma unroll
    for (int i = 0; i < 4; ++i) af[i] = *(const short8*)(sA + (wm + i * 16 + fr) * 40 + qd * 8);
#pragma unroll
    for (int j = 0; j < 4; ++j) bfr[j] = *(const short8*)(sB + (wn + j * 16 + fr) * 40 + qd * 8);
#pragma unroll
    for (int i = 0; i < 4; ++i)
#pragma unroll
      for (int j = 0; j < 4; ++j) acc[i][j] = MFMA16(af[i], bfr[j], acc[i][j]);
  }
}

// ---------- kernel 1: fused QKV + gate + lr projection ----------
__global__ __launch_bounds__(256) void k_gemm1(
    const u16* __restrict__ A, const u16* __restrict__ Bw,
    float* __restrict__ Qf, float* __restrict__ Kf, float* __restrict__ Vf,
    u16* __restrict__ gateb, float* __restrict__ eta,
    const float* __restrict__ lr_b, const float* __restrict__ tio) {
  __shared__ __align__(16) u16 sA[128 * 40];
  __shared__ __align__(16) u16 sB[128 * 40];
  int bm = blockIdx.x & 63, bn = blockIdx.x >> 6;
  f32x4 acc[4][4];
  gemm_core(A, Bw, bm, bn, sA, sB, acc);
  int tid = threadIdx.x, lane = tid & 63, wid = tid >> 6;
  int fr = lane & 15, qd = lane >> 4;
  int wm = (wid & 1) * 64, wn = (wid >> 1) * 64;
#pragma unroll
  for (int i = 0; i < 4; ++i) {
    int gr0 = bm * 128 + wm + i * 16 + qd * 4;
#pragma unroll
    for (int j = 0; j < 4; ++j) {
      int gc = bn * 128 + wn + j * 16 + fr;
      if (gc < 3072) {
        int p = gc >> 10, rem = gc & 1023, hd = rem >> 6, dd = rem & 63;
        float* dst = (p == 0) ? Qf : ((p == 1) ? Kf : Vf);
#pragma unroll
        for (int r = 0; r < 4; ++r) {
          int gr = gr0 + r;
          int b_ = gr >> 11, s = gr & 2047;
          dst[(((size_t)(b_ * 16 + hd)) * 2048 + s) * 64 + dd] = acc[i][j][r];
        }
      } else if (gc < 4096) {
        int j2 = gc - 3072;
#pragma unroll
        for (int r = 0; r < 4; ++r) {
          int gr = gr0 + r;
          float vv = acc[i][j][r];
          float gl = 0.5f * vv * (1.0f + erff(vv * 0.70710678118654752f));  // exact gelu
          gateb[(size_t)gr * 1024 + j2] = f2bf(gl);
        }
      } else if (gc < 4112) {
        int hd = gc - 4096;
        float lb = lr_b[hd];
#pragma unroll
        for (int r = 0; r < 4; ++r) {
          int gr = gr0 + r;
          int b_ = gr >> 11, s = gr & 2047, m = s & 15;
          float lm = 1.0f / (1.0f + expf(-(acc[i][j][r] + lb)));
          float tok = fmaxf(1.0f / (float)(m + 1) + tio[m], 0.0f);
          eta[((size_t)(b_ * 16 + hd)) * 2048 + s] = tok * lm * 0.015625f;  // /D
        }
      }
    }
  }
}

// ---------- kernel 2: Phase A — sequential W/b trajectory per head ----------
// R5: the scan is in-order-ISSUE bound (45% VALU on active CUs). 16 waves
// (1024 thr): d splits 16 ways (4 d/wave) -> matvec & W-update per wave drop
// 4x; batch-owner waves 0-3 land on SIMDs 0-3 with 3 light co-waves each to
// hide LN/DPP/LDS stalls. u is pre-scaled by 0.25 (fold into fmac forms).
__global__ __launch_bounds__(1024) void k_phaseA(
    const float* __restrict__ Kf, const float* __restrict__ Vf, const float* __restrict__ eta,
    const float* __restrict__ W_init, const float* __restrict__ b_init,
    const float* __restrict__ ttt_w, const float* __restrict__ ttt_b,
    float* __restrict__ Wseq, float* __restrict__ bseq) {
  __shared__ float pbuf[2][16][4][64];  // [buf][d-slice wave][batch][e]
  __shared__ float ush[2][4][64];       // [buf][batch][e], u pre-scaled by 0.25
  int h = blockIdx.x;
  int tid = threadIdx.x, lane = tid & 63;
  int wu = __builtin_amdgcn_readfirstlane(tid >> 6);  // wave-uniform wave id 0..15
  int wu4 = wu * 4;
  bool owner = (wu < 4);  // wave-uniform branch
  float Wreg[4];
#pragma unroll
  for (int i = 0; i < 4; ++i) Wreg[i] = W_init[(size_t)h * 4096 + (wu4 + i) * 64 + lane];
  float bcur = b_init[h * 64 + lane];
  float g = ttt_w[h * 64 + lane], tb = ttt_b[h * 64 + lane];
  // last-row bases (batch 0..3); row n at float offset n*1024
  const float* kb0 = Kf + (((size_t)(0 * 16 + h)) * 2048 + 15) * 64;
  const float* kb1 = Kf + (((size_t)(1 * 16 + h)) * 2048 + 15) * 64;
  const float* kb2 = Kf + (((size_t)(2 * 16 + h)) * 2048 + 15) * 64;
  const float* kb3 = Kf + (((size_t)(3 * 16 + h)) * 2048 + 15) * 64;
  const float* vbw = Vf + (((size_t)(wu * 16 + h)) * 2048 + 15) * 64;   // owners only
  const float* erow = eta + ((size_t)(wu * 16 + h)) * 2048 + 15;       // owners only

  // ---- prologue: rows 0 and 1 lane-resident; z^0 = K^0 W_0 + b_0 ----
  float kc0 = kb0[lane], kc1 = kb1[lane], kc2 = kb2[lane], kc3 = kb3[lane];
  float kn0 = kb0[1024 + lane], kn1 = kb1[1024 + lane];
  float kn2 = kb2[1024 + lane], kn3 = kb3[1024 + lane];
  float vcur = 0.f, vnx = 0.f, ecur = 0.f, enx = 0.f;
  if (owner) {
    vcur = vbw[lane]; vnx = vbw[1024 + lane];
    ecur = erow[0]; enx = erow[16];
  }
  {
    float p0 = 0.f, p1 = 0.f, p2 = 0.f, p3 = 0.f;
#pragma unroll
    for (int i = 0; i < 4; ++i) {
      float wr = Wreg[i];
      p0 += rdlane(kc0, wu4 + i) * wr;
      p1 += rdlane(kc1, wu4 + i) * wr;
      p2 += rdlane(kc2, wu4 + i) * wr;
      p3 += rdlane(kc3, wu4 + i) * wr;
    }
    pbuf[0][wu][0][lane] = p0; pbuf[0][wu][1][lane] = p1;
    pbuf[0][wu][2][lane] = p2; pbuf[0][wu][3][lane] = p3;
  }
  __syncthreads();
  float zc = 0.f;
  if (owner) {
    float zs = 0.f;
#pragma unroll
    for (int w = 0; w < 16; ++w) zs += pbuf[0][w][wu][lane];
    zc = zs + bcur;
  }

  for (int n = 0; n < 128; ++n) {
    int bi = n & 1, pi = (n + 1) & 1;
    int nf = (n < 126) ? n + 2 : 127;  // 2-ahead prefetch row
    size_t nfoff = (size_t)nf * 1024;
    // A. issue 2-ahead prefetch (lands by iter n+1)
    float kf0 = kb0[nfoff + lane], kf1 = kb1[nfoff + lane];
    float kf2 = kb2[nfoff + lane], kf3 = kb3[nfoff + lane];
    float vfx = 0.f, efx = 0.f;
    if (owner) { vfx = vbw[nfoff + lane]; efx = erow[nf * 16]; }
    // B. snapshot W_n / b_n (drain overlaps this step's work); Wseq[h][n][e][d]
    {
      float4 t4;
      t4.x = Wreg[0]; t4.y = Wreg[1]; t4.z = Wreg[2]; t4.w = Wreg[3];
      *(float4*)(Wseq + (((size_t)h * 128 + n) * 64 + lane) * 64 + wu4) = t4;
      if (wu == 0) bseq[((size_t)h * 128 + n) * 64 + lane] = bcur;
    }
    // C. partials K^{n+1} . W_n via readlane broadcast (kn landed last iter)
    {
      float p0 = 0.f, p1 = 0.f, p2 = 0.f, p3 = 0.f;
#pragma unroll
      for (int i = 0; i < 4; ++i) {
        float wr = Wreg[i];
        p0 += rdlane(kn0, wu4 + i) * wr;
        p1 += rdlane(kn1, wu4 + i) * wr;
        p2 += rdlane(kn2, wu4 + i) * wr;
        p3 += rdlane(kn3, wu4 + i) * wr;
      }
      pbuf[pi][wu][0][lane] = p0; pbuf[pi][wu][1][lane] = p1;
      pbuf[pi][wu][2][lane] = p2; pbuf[pi][wu][3][lane] = p3;
    }
    float D0 = 0.f, D1 = 0.f, D2 = 0.f, D3 = 0.f;
    if (owner) {
      // D. D-dots: own next-row against all current rows
      float kon = (wu == 0) ? kn0 : (wu == 1) ? kn1 : (wu == 2) ? kn2 : kn3;
      D0 = wred64(kon * kc0); D1 = wred64(kon * kc1);
      D2 = wred64(kon * kc2); D3 = wred64(kon * kc3);
      // E. LN-vjp on z^n (wave wu handles batch wu's last row)
      float kl = (wu == 0) ? kc0 : (wu == 1) ? kc1 : (wu == 2) ? kc2 : kc3;
      float s1 = wred64(zc), s2 = wred64(zc * zc);
      float mu = s1 * 0.015625f;
      float var = s2 * 0.015625f - mu * mu;
      float rstd = rsqrtf(var + 1e-5f);
      float xc = zc - mu;
      float ln = xc * rstd * g + tb;
      float go = ln - (vcur - kl);
      float gxn = go * g;
      float sa = wred64(gxn * xc), sb_ = wred64(gxn);
      float gvar = -0.5f * sa * rstd * rstd * rstd;
      float gmu = -sb_ * rstd;  // sum(xc) term ~0, dropped
      float gz = gxn * rstd + gvar * 2.0f * xc * 0.015625f + gmu * 0.015625f;
      ush[bi][wu][lane] = 0.25f * ecur * gz;  // pre-scaled u
    }
    __syncthreads();
    // F. u exchange; owners: b update + z^{n+1} assembly
    float u0 = ush[bi][0][lane], u1 = ush[bi][1][lane];
    float u2 = ush[bi][2][lane], u3 = ush[bi][3][lane];
    if (owner) {
      float bnext = bcur - (u0 + u1 + u2 + u3);
      float zs = 0.f;
#pragma unroll
      for (int w = 0; w < 16; ++w) zs += pbuf[pi][w][wu][lane];
      zc = zs - (D0 * u0 + D1 * u1 + D2 * u2 + D3 * u3) + bnext;
      bcur = bnext;
    }
    // G. W update with k^n via readlane broadcast (u pre-scaled)
#pragma unroll
    for (int i = 0; i < 4; ++i) {
      float a = rdlane(kc0, wu4 + i) * u0 + rdlane(kc1, wu4 + i) * u1 +
                rdlane(kc2, wu4 + i) * u2 + rdlane(kc3, wu4 + i) * u3;
      Wreg[i] -= a;
    }
    // H. rotate prefetch registers
    kc0 = kn0; kc1 = kn1; kc2 = kn2; kc3 = kn3;
    kn0 = kf0; kn1 = kf1; kn2 = kf2; kn3 = kf3;
    vcur = vnx; vnx = vfx; ecur = enx; enx = efx;
  }
}

// ---------- kernel 3: Phase B — per-(minibatch, head) full outputs via MFMA hi/lo ----------
__global__ __launch_bounds__(256) void k_phaseB(
    const float* __restrict__ Qf, const float* __restrict__ Kf, const float* __restrict__ Vf,
    const float* __restrict__ eta, const float* __restrict__ Wseq, const float* __restrict__ bseq,
    const float* __restrict__ ttt_w, const float* __restrict__ ttt_b, float* __restrict__ yout) {
  __shared__ __align__(16) u16 WtH[64 * 72], WtL[64 * 72];   // W^T [e][d] hi/lo bf16, pad 72
  __shared__ __align__(16) u16 gzH[4][64 * 24], gzL[4][64 * 24];  // gZ^T [e][m] per wave
  __shared__ __align__(16) float At[4][16 * 20];             // Attn^T [n][m] per wave
  __shared__ float bsh[64];
  int bx = blockIdx.x;
  int n = bx & 127, h = bx >> 7;
  int tid = threadIdx.x, lane = tid & 63, wv = tid >> 6;  // wave = batch
  int fr = lane & 15, qd = lane >> 4;

  // stage W_n (already [e][d]) -> hi/lo bf16 LDS
  {
    int e = tid >> 2, d0 = (tid & 3) << 4;
    const float* src = Wseq + (((size_t)h * 128 + n) * 64 + e) * 64 + d0;
#pragma unroll
    for (int gsub = 0; gsub < 2; ++gsub) {
      u16 hb[8], lb_[8];
#pragma unroll
      for (int i = 0; i < 8; i += 4) {
        float4 v = *(const float4*)(src + gsub * 8 + i);
        f2hl(v.x, hb[i], lb_[i]);
        f2hl(v.y, hb[i + 1], lb_[i + 1]);
        f2hl(v.z, hb[i + 2], lb_[i + 2]);
        f2hl(v.w, hb[i + 3], lb_[i + 3]);
      }
      uint4 ph, pl;
      ph.x = hb[0] | ((u32)hb[1] << 16); ph.y = hb[2] | ((u32)hb[3] << 16);
      ph.z = hb[4] | ((u32)hb[5] << 16); ph.w = hb[6] | ((u32)hb[7] << 16);
      pl.x = lb_[0] | ((u32)lb_[1] << 16); pl.y = lb_[2] | ((u32)lb_[3] << 16);
      pl.z = lb_[4] | ((u32)lb_[5] << 16); pl.w = lb_[6] | ((u32)lb_[7] << 16);
      *(uint4*)(&WtH[e * 72 + d0 + gsub * 8]) = ph;
      *(uint4*)(&WtL[e * 72 + d0 + gsub * 8]) = pl;
    }
    if (tid < 64) bsh[tid] = bseq[((size_t)h * 128 + n) * 64 + tid];
  }
  __syncthreads();

  const size_t bh = (size_t)(wv * 16 + h);
  const float* Qp = Qf + (bh * 2048 + (size_t)n * 16) * 64;
  const float* Kp = Kf + (bh * 2048 + (size_t)n * 16) * 64;
  const float* Vp = Vf + (bh * 2048 + (size_t)n * 16) * 64;
  const float* ep = eta + bh * 2048 + n * 16;

  // Q/K A-operand fragments (also reused as B for Attn): [m=fr][k = s*32 + qd*8 + j]
  short8 qH[2], qL[2], kH[2], kL[2];
#pragma unroll
  for (int s = 0; s < 2; ++s) {
    const float* p1 = Qp + fr * 64 + s * 32 + qd * 8;
    const float* p2 = Kp + fr * 64 + s * 32 + qd * 8;
#pragma unroll
    for (int j = 0; j < 8; ++j) {
      u16 hb, lb_;
      f2hl(p1[j], hb, lb_); qH[s][j] = (short)hb; qL[s][j] = (short)lb_;
      f2hl(p2[j], hb, lb_); kH[s][j] = (short)hb; kL[s][j] = (short)lb_;
    }
  }

  // Z = K@W + b  (C-layout: row m = qd*4+r, col e = t*16+fr)
  f32x4 Zt[4];
#pragma unroll
  for (int t = 0; t < 4; ++t) {
    f32x4 a = {0.f, 0.f, 0.f, 0.f};
#pragma unroll
    for (int s = 0; s < 2; ++s) {
      short8 wH = *(const short8*)(&WtH[(t * 16 + fr) * 72 + s * 32 + qd * 8]);
      short8 wL = *(const short8*)(&WtL[(t * 16 + fr) * 72 + s * 32 + qd * 8]);
      a = MFMA16(kH[s], wH, a);
      a = MFMA16(kL[s], wH, a);
      a = MFMA16(kH[s], wL, a);
    }
    float bv = bsh[t * 16 + fr];
    a[0] += bv; a[1] += bv; a[2] += bv; a[3] += bv;
    Zt[t] = a;
  }
  // Attn = Q@K^T (16x16)
  f32x4 Atn = {0.f, 0.f, 0.f, 0.f};
#pragma unroll
  for (int s = 0; s < 2; ++s) {
    Atn = MFMA16(qH[s], kH[s], Atn);
    Atn = MFMA16(qL[s], kH[s], Atn);
    Atn = MFMA16(qH[s], kL[s], Atn);
  }

  // LN(Z) + vjp
  float gw[4], gb[4];
#pragma unroll
  for (int t = 0; t < 4; ++t) {
    gw[t] = ttt_w[h * 64 + t * 16 + fr];
    gb[t] = ttt_b[h * 64 + t * 16 + fr];
  }
  float s1[4], s2[4];
#pragma unroll
  for (int r = 0; r < 4; ++r) {
    float a0 = Zt[0][r], a1 = Zt[1][r], a2 = Zt[2][r], a3 = Zt[3][r];
    s1[r] = a0 + a1 + a2 + a3;
    s2[r] = a0 * a0 + a1 * a1 + a2 * a2 + a3 * a3;
  }
#pragma unroll
  for (int off = 1; off <= 8; off <<= 1) {
#pragma unroll
    for (int r = 0; r < 4; ++r) {
      s1[r] += __shfl_xor(s1[r], off, 64);
      s2[r] += __shfl_xor(s2[r], off, 64);
    }
  }
  float mu[4], rstd[4];
#pragma unroll
  for (int r = 0; r < 4; ++r) {
    mu[r] = s1[r] * 0.015625f;
    float var = s2[r] * 0.015625f - mu[r] * mu[r];
    rstd[r] = rsqrtf(var + 1e-5f);
  }
  float xc[4][4], gxn[4][4];
  float s3[4] = {0, 0, 0, 0}, s4[4] = {0, 0, 0, 0}, s5[4] = {0, 0, 0, 0};
#pragma unroll
  for (int t = 0; t < 4; ++t) {
#pragma unroll
    for (int r = 0; r < 4; ++r) {
      float z = Zt[t][r];
      float x = z - mu[r];
      xc[t][r] = x;
      float ln = x * rstd[r] * gw[t] + gb[t];
      float vV = Vp[(qd * 4 + r) * 64 + t * 16 + fr];
      float vK = Kp[(qd * 4 + r) * 64 + t * 16 + fr];
      float go = ln - (vV - vK);
      float gx = go * gw[t];
      gxn[t][r] = gx;
      s3[r] += gx * x;
      s4[r] += gx;
      s5[r] += x;
    }
  }
#pragma unroll
  for (int off = 1; off <= 8; off <<= 1) {
#pragma unroll
    for (int r = 0; r < 4; ++r) {
      s3[r] += __shfl_xor(s3[r], off, 64);
      s4[r] += __shfl_xor(s4[r], off, 64);
      s5[r] += __shfl_xor(s5[r], off, 64);
    }
  }
  float gvar[4], gmu[4];
#pragma unroll
  for (int r = 0; r < 4; ++r) {
    float r3 = rstd[r] * rstd[r] * rstd[r];
    gvar[r] = -0.5f * s3[r] * r3;
    gmu[r] = -s4[r] * rstd[r] + gvar[r] * (-2.0f * s5[r]) * 0.015625f;
  }
  // gZ -> LDS transposed [e][m], hi/lo bf16
#pragma unroll
  for (int t = 0; t < 4; ++t) {
    u16 hb[4], lb_[4];
#pragma unroll
    for (int r = 0; r < 4; ++r) {
      float gz = gxn[t][r] * rstd[r] + gvar[r] * 2.0f * xc[t][r] * 0.015625f + gmu[r] * 0.015625f;
      f2hl(gz, hb[r], lb_[r]);
    }
    uint2 ph, pl;
    ph.x = hb[0] | ((u32)hb[1] << 16); ph.y = hb[2] | ((u32)hb[3] << 16);
    pl.x = lb_[0] | ((u32)lb_[1] << 16); pl.y = lb_[2] | ((u32)lb_[3] << 16);
    *(uint2*)(&gzH[wv][(t * 16 + fr) * 24 + qd * 4]) = ph;
    *(uint2*)(&gzL[wv][(t * 16 + fr) * 24 + qd * 4]) = pl;
  }
  // Attn -> LDS transposed At[n][m]
  *(f32x4*)(&At[wv][fr * 20 + qd * 4]) = Atn;

  // Combined A = em[m]*(1 + tril(Attn))[m][n] for n<=m  (covers tril1 + Attn terms)
  float em = ep[fr];
  short8 aH = s8zero(), aL = s8zero();
  if (qd < 2) {
#pragma unroll
    for (int j = 0; j < 8; ++j) {
      int nn = qd * 8 + j;
      float av = 0.0f;
      if (nn <= fr) av = em * (1.0f + At[wv][nn * 20 + fr]);
      u16 hb, lb_;
      f2hl(av, hb, lb_);
      aH[j] = (short)hb;
      aL[j] = (short)lb_;
    }
  }
  // Zb = Q@W + b - Acomb@gZ
  f32x4 Ob[4];
#pragma unroll
  for (int t = 0; t < 4; ++t) {
    f32x4 a = {0.f, 0.f, 0.f, 0.f};
#pragma unroll
    for (int s = 0; s < 2; ++s) {
      short8 wH = *(const short8*)(&WtH[(t * 16 + fr) * 72 + s * 32 + qd * 8]);
      short8 wL = *(const short8*)(&WtL[(t * 16 + fr) * 72 + s * 32 + qd * 8]);
      a = MFMA16(qH[s], wH, a);
      a = MFMA16(qL[s], wH, a);
      a = MFMA16(qH[s], wL, a);
    }
    short8 gH = s8zero(), gL = s8zero();
    if (qd < 2) {
      gH = *(const short8*)(&gzH[wv][(t * 16 + fr) * 24 + qd * 8]);
      gL = *(const short8*)(&gzL[wv][(t * 16 + fr) * 24 + qd * 8]);
    }
    f32x4 c = {0.f, 0.f, 0.f, 0.f};
    c = MFMA16(aH, gH, c);
    c = MFMA16(aL, gH, c);
    c = MFMA16(aH, gL, c);
    float bv = bsh[t * 16 + fr];
#pragma unroll
    for (int r = 0; r < 4; ++r) Ob[t][r] = a[r] - c[r] + bv;
  }
  // out = Q + LN(Zb)
#pragma unroll
  for (int r = 0; r < 4; ++r) {
    float a0 = Ob[0][r], a1 = Ob[1][r], a2 = Ob[2][r], a3 = Ob[3][r];
    s1[r] = a0 + a1 + a2 + a3;
    s2[r] = a0 * a0 + a1 * a1 + a2 * a2 + a3 * a3;
  }
#pragma unroll
  for (int off = 1; off <= 8; off <<= 1) {
#pragma unroll
    for (int r = 0; r < 4; ++r) {
      s1[r] += __shfl_xor(s1[r], off, 64);
      s2[r] += __shfl_xor(s2[r], off, 64);
    }
  }
#pragma unroll
  for (int r = 0; r < 4; ++r) {
    mu[r] = s1[r] * 0.015625f;
    float var = s2[r] * 0.015625f - mu[r] * mu[r];
    rstd[r] = rsqrtf(var + 1e-5f);
  }
#pragma unroll
  for (int t = 0; t < 4; ++t) {
#pragma unroll
    for (int r = 0; r < 4; ++r) {
      float ln = (Ob[t][r] - mu[r]) * rstd[r] * gw[t] + gb[t];
      float qv = Qp[(qd * 4 + r) * 64 + t * 16 + fr];
      yout[((size_t)wv * 2048 + n * 16 + qd * 4 + r) * 1024 + h * 64 + t * 16 + fr] = qv + ln;
    }
  }
}

// ---------- kernel 4: post-LN + gate -> zb (bf16) ----------
__global__ __launch_bounds__(256) void k_postln(
    const float* __restrict__ yf, const u16* __restrict__ gateb,
    const float* __restrict__ post_w, const float* __restrict__ post_b, u16* __restrict__ zb) {
  __shared__ float red[8];
  int row = blockIdx.x, tid = threadIdx.x;
  int lane = tid & 63, wid = tid >> 6;
  const float* yr = yf + (size_t)row * 1024;
  float4 v = *(const float4*)(yr + tid * 4);
  float s1 = v.x + v.y + v.z + v.w;
  float s2 = v.x * v.x + v.y * v.y + v.z * v.z + v.w * v.w;
  s1 = wsum64(s1);
  s2 = wsum64(s2);
  if (lane == 0) { red[wid] = s1; red[4 + wid] = s2; }
  __syncthreads();
  s1 = red[0] + red[1] + red[2] + red[3];
  s2 = red[4] + red[5] + red[6] + red[7];
  float mu = s1 * (1.0f / 1024.0f);
  float var = s2 * (1.0f / 1024.0f) - mu * mu;
  float rstd = rsqrtf(var + 1e-5f);
  float vals[4] = {v.x, v.y, v.z, v.w};
  u16 ov[4];
#pragma unroll
  for (int i = 0; i < 4; ++i) {
    int cc = tid * 4 + i;
    float yn = (vals[i] - mu) * rstd * post_w[cc] + post_b[cc];
    float gt = bf2f(gateb[(size_t)row * 1024 + cc]);
    ov[i] = f2bf(gt * yn);
  }
  ushort4 o;
  o.x = ov[0]; o.y = ov[1]; o.z = ov[2]; o.w = ov[3];
  *(ushort4*)(zb + (size_t)row * 1024 + tid * 4) = o;
}

// ---------- kernel 5: output GEMM ----------
__global__ __launch_bounds__(256) void k_gemm2(const u16* __restrict__ A, const u16* __restrict__ Bw,
                                               float* __restrict__ Out) {
  __shared__ __align__(16) u16 sA[128 * 40];
  __shared__ __align__(16) u16 sB[128 * 40];
  int bm = blockIdx.x & 63, bn = blockIdx.x >> 6;
  f32x4 acc[4][4];
  gemm_core(A, Bw, bm, bn, sA, sB, acc);
  int tid = threadIdx.x, lane = tid & 63, wid = tid >> 6;
  int fr = lane & 15, qd = lane >> 4;
  int wm = (wid & 1) * 64, wn = (wid >> 1) * 64;
#pragma unroll
  for (int i = 0; i < 4; ++i) {
    int gr0 = bm * 128 + wm + i * 16 + qd * 4;
#pragma unroll
    for (int j = 0; j < 4; ++j) {
      int gc = bn * 128 + wn + j * 16 + fr;
#pragma unroll
      for (int r = 0; r < 4; ++r) Out[(size_t)(gr0 + r) * 1024 + gc] = acc[i][j][r];
    }
  }
}

// ---------- workspace layout (bytes) ----------
#define OFF_XB    ((size_t)0)          // 8192*1024 bf16      = 16777216
#define OFF_WCAT  ((size_t)16777216)   // 4224*1024 bf16      =  8650752
#define OFF_WOB   ((size_t)25427968)   // 1024*1024 bf16      =  2097152
#define OFF_Q     ((size_t)27525120)   // 4*16*2048*64 f32    = 33554432
#define OFF_K     ((size_t)61079552)
#define OFF_V     ((size_t)94633984)
#define OFF_GATE  ((size_t)128188416)  // 8192*1024 bf16
#define OFF_ETA   ((size_t)144965632)  // 4*16*2048 f32
#define OFF_WSEQ  ((size_t)145489920)  // 16*128*64*64 f32
#define OFF_BSEQ  ((size_t)179044352)  // 16*128*64 f32
#define OFF_Y     ((size_t)179568640)  // 8192*1024 f32
#define OFF_ZB    ((size_t)213123072)  // 8192*1024 bf16  (end = 229900288)

extern "C" void kernel_launch(void* const* d_in, const int* in_sizes, int n_in,
                              void* d_out, int out_size, void* d_ws, size_t ws_size,
                              hipStream_t stream) {
  const float* x    = (const float*)d_in[0];
  const float* Wq   = (const float*)d_in[1];
  const float* Wk   = (const float*)d_in[2];
  const float* Wv   = (const float*)d_in[3];
  const float* Wini = (const float*)d_in[4];
  const float* bini = (const float*)d_in[5];
  const float* ttw  = (const float*)d_in[6];
  const float* ttb  = (const float*)d_in[7];
  const float* pw   = (const float*)d_in[8];
  const float* pb   = (const float*)d_in[9];
  const float* lrw  = (const float*)d_in[10];
  const float* lrb  = (const float*)d_in[11];
  const float* tio  = (const float*)d_in[12];
  const float* Wg   = (const float*)d_in[13];
  const float* Wo   = (const float*)d_in[14];
  (void)in_sizes; (void)n_in; (void)out_size; (void)ws_size;
  float* out = (float*)d_out;
  char* ws = (char*)d_ws;
  u16* xb    = (u16*)(ws + OFF_XB);
  u16* Wcat  = (u16*)(ws + OFF_WCAT);
  u16* Wob   = (u16*)(ws + OFF_WOB);
  float* Qf  = (float*)(ws + OFF_Q);
  float* Kf  = (float*)(ws + OFF_K);
  float* Vf  = (float*)(ws + OFF_V);
  u16* gateb = (u16*)(ws + OFF_GATE);
  float* eta = (float*)(ws + OFF_ETA);
  float* Wsq = (float*)(ws + OFF_WSEQ);
  float* bsq = (float*)(ws + OFF_BSEQ);
  float* yf  = (float*)(ws + OFF_Y);
  u16* zbuf  = (u16*)(ws + OFF_ZB);

  hipLaunchKernelGGL(k_cast, dim3(13440), dim3(256), 0, stream, x, Wq, Wk, Wv, Wg, lrw, Wo, xb, Wcat, Wob);
  hipLaunchKernelGGL(k_gemm1, dim3(64 * 33), dim3(256), 0, stream, xb, Wcat, Qf, Kf, Vf, gateb, eta, lrb, tio);
  hipLaunchKernelGGL(k_phaseA, dim3(16), dim3(1024), 0, stream, Kf, Vf, eta, Wini, bini, ttw, ttb, Wsq, bsq);
  hipLaunchKernelGGL(k_phaseB, dim3(2048), dim3(256), 0, stream, Qf, Kf, Vf, eta, Wsq, bsq, ttw, ttb, yf);
  hipLaunchKernelGGL(k_postln, dim3(8192), dim3(256), 0, stream, yf, gateb, pw, pb, zbuf);
  hipLaunchKernelGGL(k_gemm2, dim3(64 * 8), dim3(256), 0, stream, zbuf, Wob, out);
}

// Round 6
// 397.691 us; speedup vs baseline: 1.5302x; 1.2441x over previous
//
#include <hip/hip_runtime.h>
#include <hip/hip_bf16.h>
#include <math.h>

typedef unsigned short u16;
typedef unsigned int u32;
typedef __attribute__((ext_vector_type(8))) short short8;
typedef __attribute__((ext_vector_type(4))) float f32x4;

#define MFMA16(a,b,c) __builtin_amdgcn_mfma_f32_16x16x32_bf16((a),(b),(c),0,0,0)

// ---------- helpers ----------
__device__ __forceinline__ u16 f2bf(float f) {
  u32 u = __float_as_uint(f);
  u32 r = (u + 0x7FFFu + ((u >> 16) & 1u)) >> 16;
  return (u16)r;
}
__device__ __forceinline__ float bf2f(u16 h) { return __uint_as_float(((u32)h) << 16); }
__device__ __forceinline__ void f2hl(float f, u16& h, u16& l) {
  h = f2bf(f);
  l = f2bf(f - bf2f(h));
}
__device__ __forceinline__ float wsum64(float v) {
#pragma unroll
  for (int off = 32; off > 0; off >>= 1) v += __shfl_xor(v, off, 64);
  return v;
}
// DPP wave-64 sum: row_shr 1/2/4/8 + row_bcast15/31; broadcast via readlane.
__device__ __forceinline__ float wred64(float v) {
  v += __int_as_float(__builtin_amdgcn_update_dpp(0, __float_as_int(v), 0x111, 0xf, 0xf, true));
  v += __int_as_float(__builtin_amdgcn_update_dpp(0, __float_as_int(v), 0x112, 0xf, 0xf, true));
  v += __int_as_float(__builtin_amdgcn_update_dpp(0, __float_as_int(v), 0x114, 0xf, 0xf, true));
  v += __int_as_float(__builtin_amdgcn_update_dpp(0, __float_as_int(v), 0x118, 0xf, 0xf, true));
  v += __int_as_float(__builtin_amdgcn_update_dpp(0, __float_as_int(v), 0x142, 0xa, 0xf, true));
  v += __int_as_float(__builtin_amdgcn_update_dpp(0, __float_as_int(v), 0x143, 0xc, 0xf, true));
  return __int_as_float(__builtin_amdgcn_readlane(__float_as_int(v), 63));
}
__device__ __forceinline__ float rdlane(float v, int lane) {
  return __int_as_float(__builtin_amdgcn_readlane(__float_as_int(v), lane));
}
__device__ __forceinline__ short8 s8zero() {
  short8 v;
#pragma unroll
  for (int j = 0; j < 8; ++j) v[j] = 0;
  return v;
}

// ---------- kernel 0: cast inputs to bf16 (xb, Wcat[4224x1024], Wob) ----------
__global__ __launch_bounds__(256) void k_cast(
    const float* __restrict__ x, const float* __restrict__ Wq, const float* __restrict__ Wk,
    const float* __restrict__ Wv, const float* __restrict__ Wg, const float* __restrict__ lrw,
    const float* __restrict__ Wo, u16* __restrict__ xb, u16* __restrict__ Wcat, u16* __restrict__ Wob) {
  int c = blockIdx.x * 256 + threadIdx.x;
  float4 v = make_float4(0.f, 0.f, 0.f, 0.f);
  u16* dst;
  if (c < 2097152) {
    v = *(const float4*)(x + (size_t)c * 4);
    dst = xb + (size_t)c * 4;
  } else if (c < 2097152 + 1081344) {
    int c2 = c - 2097152;
    int base = c2 * 4;
    int nr = base >> 10, col = base & 1023;
    if (nr < 1024)      v = *(const float4*)(Wq  + (size_t)nr * 1024 + col);
    else if (nr < 2048) v = *(const float4*)(Wk  + (size_t)(nr - 1024) * 1024 + col);
    else if (nr < 3072) v = *(const float4*)(Wv  + (size_t)(nr - 2048) * 1024 + col);
    else if (nr < 4096) v = *(const float4*)(Wg  + (size_t)(nr - 3072) * 1024 + col);
    else if (nr < 4112) v = *(const float4*)(lrw + (size_t)(nr - 4096) * 1024 + col);
    dst = Wcat + (size_t)base;
  } else {
    int c2 = c - (2097152 + 1081344);
    v = *(const float4*)(Wo + (size_t)c2 * 4);
    dst = Wob + (size_t)c2 * 4;
  }
  ushort4 o;
  o.x = f2bf(v.x); o.y = f2bf(v.y); o.z = f2bf(v.z); o.w = f2bf(v.w);
  *(ushort4*)dst = o;
}

// ---------- 256-thread GEMM core (128x128 tile) ----------
__device__ __forceinline__ void gemm_core(const u16* __restrict__ A, const u16* __restrict__ Bw,
                                          int bm, int bn, u16* sA, u16* sB, f32x4 acc[4][4]) {
  int tid = threadIdx.x;
  int lane = tid & 63, wid = tid >> 6;
  int fr = lane & 15, qd = lane >> 4;
  int wm = (wid & 1) * 64, wn = (wid >> 1) * 64;
#pragma unroll
  for (int i = 0; i < 4; ++i)
#pragma unroll
    for (int j = 0; j < 4; ++j) {
      f32x4 zz = {0.f, 0.f, 0.f, 0.f};
      acc[i][j] = zz;
    }
  for (int k0 = 0; k0 < 1024; k0 += 32) {
    __syncthreads();
#pragma unroll
    for (int cc = 0; cc < 2; ++cc) {
      int ch = tid + cc * 256;
      int row = ch >> 2, kp = (ch & 3) << 3;
      *(uint4*)(sA + row * 40 + kp) = *(const uint4*)(A + (size_t)(bm * 128 + row) * 1024 + k0 + kp);
      *(uint4*)(sB + row * 40 + kp) = *(const uint4*)(Bw + (size_t)(bn * 128 + row) * 1024 + k0 + kp);
    }
    __syncthreads();
    short8 af[4], bfr[4];
#pragma unroll
    for (int i = 0; i < 4; ++i) af[i] = *(const short8*)(sA + (wm + i * 16 + fr) * 40 + qd * 8);
#pragma unroll
    for (int j = 0; j < 4; ++j) bfr[j] = *(const short8*)(sB + (wn + j * 16 + fr) * 40 + qd * 8);
#pragma unroll
    for (int i = 0; i < 4; ++i)
#pragma unroll
      for (int j = 0; j < 4; ++j) acc[i][j] = MFMA16(af[i], bfr[j], acc[i][j]);
  }
}

// ---------- kernel L: last-row K/V/eta slices (512 gathered rows) ----------
// A rows gathered: r -> xrow = (r>>7)*2048 + (r&127)*16 + 15. B: Wcat rows
// 1024+bn*128 (bn<16 -> K,V cols) or 4096 (bn==16 -> lr cols).
__global__ __launch_bounds__(256) void k_lastrow(
    const u16* __restrict__ xb, const u16* __restrict__ Wcat,
    float* __restrict__ Klast, float* __restrict__ Vlast, float* __restrict__ etalast,
    const float* __restrict__ lr_b, const float* __restrict__ tio) {
  __shared__ __align__(16) u16 sA[128 * 40];
  __shared__ __align__(16) u16 sB[128 * 40];
  int g = blockIdx.x;
  int bm = g & 3, bn = g >> 2;  // bm 0..3, bn 0..16
  int bcol0 = (bn < 16) ? (1024 + bn * 128) : 4096;
  int tid = threadIdx.x, lane = tid & 63, wid = tid >> 6;
  int fr = lane & 15, qd = lane >> 4;
  int wm = (wid & 1) * 64, wn = (wid >> 1) * 64;
  f32x4 acc[4][4];
#pragma unroll
  for (int i = 0; i < 4; ++i)
#pragma unroll
    for (int j = 0; j < 4; ++j) {
      f32x4 zz = {0.f, 0.f, 0.f, 0.f};
      acc[i][j] = zz;
    }
  for (int k0 = 0; k0 < 1024; k0 += 32) {
    __syncthreads();
#pragma unroll
    for (int cc = 0; cc < 2; ++cc) {
      int ch = tid + cc * 256;
      int row = ch >> 2, kp = (ch & 3) << 3;
      int r = bm * 128 + row;
      int xrow = (r >> 7) * 2048 + (r & 127) * 16 + 15;
      *(uint4*)(sA + row * 40 + kp) = *(const uint4*)(xb + (size_t)xrow * 1024 + k0 + kp);
      *(uint4*)(sB + row * 40 + kp) = *(const uint4*)(Wcat + (size_t)(bcol0 + row) * 1024 + k0 + kp);
    }
    __syncthreads();
    short8 af[4], bfr[4];
#pragma unroll
    for (int i = 0; i < 4; ++i) af[i] = *(const short8*)(sA + (wm + i * 16 + fr) * 40 + qd * 8);
#pragma unroll
    for (int j = 0; j < 4; ++j) bfr[j] = *(const short8*)(sB + (wn + j * 16 + fr) * 40 + qd * 8);
#pragma unroll
    for (int i = 0; i < 4; ++i)
#pragma unroll
      for (int j = 0; j < 4; ++j) acc[i][j] = MFMA16(af[i], bfr[j], acc[i][j]);
  }
  float tok15 = fmaxf(1.0f / 16.0f + tio[15], 0.0f);
#pragma unroll
  for (int i = 0; i < 4; ++i) {
    int gr0 = bm * 128 + wm + i * 16 + qd * 4;
#pragma unroll
    for (int j = 0; j < 4; ++j) {
      if (bn < 16) {
        int kv = bcol0 - 1024 + wn + j * 16 + fr;  // 0..2047
        int sel = kv >> 10, rem = kv & 1023, hd = rem >> 6, dd = rem & 63;
        float* dst = sel ? Vlast : Klast;
#pragma unroll
        for (int r = 0; r < 4; ++r) {
          int gr = gr0 + r;
          int b_ = gr >> 7, n = gr & 127;
          dst[((size_t)(b_ * 16 + hd) * 128 + n) * 64 + dd] = acc[i][j][r];
        }
      } else if (wn == 0 && j == 0) {
        int hd = fr;  // 0..15
        float lb = lr_b[hd];
#pragma unroll
        for (int r = 0; r < 4; ++r) {
          int gr = gr0 + r;
          int b_ = gr >> 7, n = gr & 127;
          float lm = 1.0f / (1.0f + expf(-(acc[i][j][r] + lb)));
          etalast[(size_t)(b_ * 16 + hd) * 128 + n] = tok15 * lm * 0.015625f;
        }
      }
    }
  }
}

// ---------- fused roles ----------
// phaseA role (blocks 0..15): R5 scan, inputs from compact Klast/Vlast/etalast.
__device__ void phaseA_role(
    char* smem, int h,
    const float* __restrict__ Klast, const float* __restrict__ Vlast,
    const float* __restrict__ etalast,
    const float* __restrict__ W_init, const float* __restrict__ b_init,
    const float* __restrict__ ttt_w, const float* __restrict__ ttt_b,
    float* __restrict__ Wseq, float* __restrict__ bseq) {
  float* pb = (float*)smem;                    // pbuf[2][16][4][64] = 32768 B
  float* us = (float*)(smem + 32768);          // ush[2][4][64] = 2048 B
#define PBUF(bf, w, b, l) pb[(((bf) * 16 + (w)) * 4 + (b)) * 64 + (l)]
#define USH(bf, b, l) us[((bf) * 4 + (b)) * 64 + (l)]
  int tid = threadIdx.x, lane = tid & 63;
  int wu = __builtin_amdgcn_readfirstlane(tid >> 6);  // 0..15
  int wu4 = wu * 4;
  bool owner = (wu < 4);
  float Wreg[4];
#pragma unroll
  for (int i = 0; i < 4; ++i) Wreg[i] = W_init[(size_t)h * 4096 + (wu4 + i) * 64 + lane];
  float bcur = b_init[h * 64 + lane];
  float g = ttt_w[h * 64 + lane], tb = ttt_b[h * 64 + lane];
  const float* kb0 = Klast + (size_t)(0 * 16 + h) * 128 * 64;  // row n at n*64
  const float* kb1 = Klast + (size_t)(1 * 16 + h) * 128 * 64;
  const float* kb2 = Klast + (size_t)(2 * 16 + h) * 128 * 64;
  const float* kb3 = Klast + (size_t)(3 * 16 + h) * 128 * 64;
  const float* vbw = Vlast + (size_t)(wu * 16 + h) * 128 * 64;  // owners only
  const float* erow = etalast + (size_t)(wu * 16 + h) * 128;    // owners only

  float kc0 = kb0[lane], kc1 = kb1[lane], kc2 = kb2[lane], kc3 = kb3[lane];
  float kn0 = kb0[64 + lane], kn1 = kb1[64 + lane];
  float kn2 = kb2[64 + lane], kn3 = kb3[64 + lane];
  float vcur = 0.f, vnx = 0.f, ecur = 0.f, enx = 0.f;
  if (owner) {
    vcur = vbw[lane]; vnx = vbw[64 + lane];
    ecur = erow[0]; enx = erow[1];
  }
  {
    float p0 = 0.f, p1 = 0.f, p2 = 0.f, p3 = 0.f;
#pragma unroll
    for (int i = 0; i < 4; ++i) {
      float wr = Wreg[i];
      p0 += rdlane(kc0, wu4 + i) * wr;
      p1 += rdlane(kc1, wu4 + i) * wr;
      p2 += rdlane(kc2, wu4 + i) * wr;
      p3 += rdlane(kc3, wu4 + i) * wr;
    }
    PBUF(0, wu, 0, lane) = p0; PBUF(0, wu, 1, lane) = p1;
    PBUF(0, wu, 2, lane) = p2; PBUF(0, wu, 3, lane) = p3;
  }
  __syncthreads();
  float zc = 0.f;
  if (owner) {
    float zs = 0.f;
#pragma unroll
    for (int w = 0; w < 16; ++w) zs += PBUF(0, w, wu, lane);
    zc = zs + bcur;
  }

  for (int n = 0; n < 128; ++n) {
    int bi = n & 1, pi = (n + 1) & 1;
    int nf = (n < 126) ? n + 2 : 127;
    size_t nfoff = (size_t)nf * 64;
    float kf0 = kb0[nfoff + lane], kf1 = kb1[nfoff + lane];
    float kf2 = kb2[nfoff + lane], kf3 = kb3[nfoff + lane];
    float vfx = 0.f, efx = 0.f;
    if (owner) { vfx = vbw[nfoff + lane]; efx = erow[nf]; }
    {
      float4 t4;
      t4.x = Wreg[0]; t4.y = Wreg[1]; t4.z = Wreg[2]; t4.w = Wreg[3];
      *(float4*)(Wseq + (((size_t)h * 128 + n) * 64 + lane) * 64 + wu4) = t4;
      if (wu == 0) bseq[((size_t)h * 128 + n) * 64 + lane] = bcur;
    }
    {
      float p0 = 0.f, p1 = 0.f, p2 = 0.f, p3 = 0.f;
#pragma unroll
      for (int i = 0; i < 4; ++i) {
        float wr = Wreg[i];
        p0 += rdlane(kn0, wu4 + i) * wr;
        p1 += rdlane(kn1, wu4 + i) * wr;
        p2 += rdlane(kn2, wu4 + i) * wr;
        p3 += rdlane(kn3, wu4 + i) * wr;
      }
      PBUF(pi, wu, 0, lane) = p0; PBUF(pi, wu, 1, lane) = p1;
      PBUF(pi, wu, 2, lane) = p2; PBUF(pi, wu, 3, lane) = p3;
    }
    float D0 = 0.f, D1 = 0.f, D2 = 0.f, D3 = 0.f;
    if (owner) {
      float kon = (wu == 0) ? kn0 : (wu == 1) ? kn1 : (wu == 2) ? kn2 : kn3;
      D0 = wred64(kon * kc0); D1 = wred64(kon * kc1);
      D2 = wred64(kon * kc2); D3 = wred64(kon * kc3);
      float kl = (wu == 0) ? kc0 : (wu == 1) ? kc1 : (wu == 2) ? kc2 : kc3;
      float s1 = wred64(zc), s2 = wred64(zc * zc);
      float mu = s1 * 0.015625f;
      float var = s2 * 0.015625f - mu * mu;
      float rstd = rsqrtf(var + 1e-5f);
      float xc = zc - mu;
      float ln = xc * rstd * g + tb;
      float go = ln - (vcur - kl);
      float gxn = go * g;
      float sa = wred64(gxn * xc), sb_ = wred64(gxn);
      float gvar = -0.5f * sa * rstd * rstd * rstd;
      float gmu = -sb_ * rstd;
      float gz = gxn * rstd + gvar * 2.0f * xc * 0.015625f + gmu * 0.015625f;
      USH(bi, wu, lane) = 0.25f * ecur * gz;
    }
    __syncthreads();
    float u0 = USH(bi, 0, lane), u1 = USH(bi, 1, lane);
    float u2 = USH(bi, 2, lane), u3 = USH(bi, 3, lane);
    if (owner) {
      float bnext = bcur - (u0 + u1 + u2 + u3);
      float zs = 0.f;
#pragma unroll
      for (int w = 0; w < 16; ++w) zs += PBUF(pi, w, wu, lane);
      zc = zs - (D0 * u0 + D1 * u1 + D2 * u2 + D3 * u3) + bnext;
      bcur = bnext;
    }
#pragma unroll
    for (int i = 0; i < 4; ++i) {
      float a = rdlane(kc0, wu4 + i) * u0 + rdlane(kc1, wu4 + i) * u1 +
                rdlane(kc2, wu4 + i) * u2 + rdlane(kc3, wu4 + i) * u3;
      Wreg[i] -= a;
    }
    kc0 = kn0; kc1 = kn1; kc2 = kn2; kc3 = kn3;
    kn0 = kf0; kn1 = kf1; kn2 = kf2; kn3 = kf3;
    vcur = vnx; vnx = vfx; ecur = enx; enx = efx;
  }
#undef PBUF
#undef USH
}

// gemm role (blocks 16..559): 256x256 tile, 16 waves of 64x64.
__device__ void gemm_role(
    char* smem, int g,
    const u16* __restrict__ A, const u16* __restrict__ Bw,
    float* __restrict__ Qf, float* __restrict__ Kf, float* __restrict__ Vf,
    u16* __restrict__ gateb, float* __restrict__ eta,
    const float* __restrict__ lr_b, const float* __restrict__ tio) {
  u16* sA = (u16*)smem;             // 256*40 u16 = 20480 B
  u16* sB = (u16*)(smem + 20480);   // 256*40 u16
  int bm = g & 31, bn = g >> 5;     // bm 0..31, bn 0..16
  int tid = threadIdx.x, lane = tid & 63, wid = tid >> 6;
  int fr = lane & 15, qd = lane >> 4;
  int wm = (wid & 3) * 64, wn = (wid >> 2) * 64;
  int srow = tid >> 2, kp = (tid & 3) << 3;
  const u16* aSrc = A + (size_t)(bm * 256 + srow) * 1024 + kp;
  // B rows 4224..4351 read stale ws (cols dropped in epilogue; C col depends
  // only on its own B column, so garbage cannot leak into valid outputs)
  const u16* bSrc = Bw + (size_t)(bn * 256 + srow) * 1024 + kp;
  f32x4 acc[4][4];
#pragma unroll
  for (int i = 0; i < 4; ++i)
#pragma unroll
    for (int j = 0; j < 4; ++j) {
      f32x4 zz = {0.f, 0.f, 0.f, 0.f};
      acc[i][j] = zz;
    }
  for (int k0 = 0; k0 < 1024; k0 += 32) {
    __syncthreads();
    *(uint4*)(sA + srow * 40 + kp) = *(const uint4*)(aSrc + k0);
    *(uint4*)(sB + srow * 40 + kp) = *(const uint4*)(bSrc + k0);
    __syncthreads();
    short8 af[4], bfr[4];
#pragma unroll
    for (int i = 0; i < 4; ++i) af[i] = *(const short8*)(sA + (wm + i * 16 + fr) * 40 + qd * 8);
#pragma unroll
    for (int j = 0; j < 4; ++j) bfr[j] = *(const short8*)(sB + (wn + j * 16 + fr) * 40 + qd * 8);
#pragma unroll
    for (int i = 0; i < 4; ++i)
#pragma unroll
      for (int j = 0; j < 4; ++j) acc[i][j] = MFMA16(af[i], bfr[j], acc[i][j]);
  }
#pragma unroll
  for (int i = 0; i < 4; ++i) {
    int gr0 = bm * 256 + wm + i * 16 + qd * 4;
#pragma unroll
    for (int j = 0; j < 4; ++j) {
      int gc = bn * 256 + wn + j * 16 + fr;
      if (gc < 3072) {
        int p = gc >> 10, rem = gc & 1023, hd = rem >> 6, dd = rem & 63;
        float* dst = (p == 0) ? Qf : ((p == 1) ? Kf : Vf);
#pragma unroll
        for (int r = 0; r < 4; ++r) {
          int gr = gr0 + r;
          int b_ = gr >> 11, s = gr & 2047;
          dst[(((size_t)(b_ * 16 + hd)) * 2048 + s) * 64 + dd] = acc[i][j][r];
        }
      } else if (gc < 4096) {
        int j2 = gc - 3072;
#pragma unroll
        for (int r = 0; r < 4; ++r) {
          int gr = gr0 + r;
          float vv = acc[i][j][r];
          float gl = 0.5f * vv * (1.0f + erff(vv * 0.70710678118654752f));
          gateb[(size_t)gr * 1024 + j2] = f2bf(gl);
        }
      } else if (gc < 4112) {
        int hd = gc - 4096;
        float lb = lr_b[hd];
#pragma unroll
        for (int r = 0; r < 4; ++r) {
          int gr = gr0 + r;
          int b_ = gr >> 11, s = gr & 2047, m = s & 15;
          float lm = 1.0f / (1.0f + expf(-(acc[i][j][r] + lb)));
          float tok = fmaxf(1.0f / (float)(m + 1) + tio[m], 0.0f);
          eta[((size_t)(b_ * 16 + hd)) * 2048 + s] = tok * lm * 0.015625f;
        }
      }
    }
  }
}

// ---------- kernel F: fused phaseA (blocks 0..15) || gemm1 (blocks 16..559) ----------
__global__ __launch_bounds__(1024, 1) void k_fused(
    const u16* __restrict__ xb, const u16* __restrict__ Wcat,
    float* __restrict__ Qf, float* __restrict__ Kf, float* __restrict__ Vf,
    u16* __restrict__ gateb, float* __restrict__ eta,
    const float* __restrict__ lr_b, const float* __restrict__ tio,
    const float* __restrict__ Klast, const float* __restrict__ Vlast,
    const float* __restrict__ etalast,
    const float* __restrict__ W_init, const float* __restrict__ b_init,
    const float* __restrict__ ttt_w, const float* __restrict__ ttt_b,
    float* __restrict__ Wseq, float* __restrict__ bseq) {
  __shared__ __align__(16) char smem[40960];
  if (blockIdx.x < 16) {
    phaseA_role(smem, blockIdx.x, Klast, Vlast, etalast, W_init, b_init,
                ttt_w, ttt_b, Wseq, bseq);
  } else {
    gemm_role(smem, blockIdx.x - 16, xb, Wcat, Qf, Kf, Vf, gateb, eta, lr_b, tio);
  }
}

// ---------- kernel 3: Phase B — per-(minibatch, head) full outputs via MFMA hi/lo ----------
__global__ __launch_bounds__(256) void k_phaseB(
    const float* __restrict__ Qf, const float* __restrict__ Kf, const float* __restrict__ Vf,
    const float* __restrict__ eta, const float* __restrict__ Wseq, const float* __restrict__ bseq,
    const float* __restrict__ ttt_w, const float* __restrict__ ttt_b, float* __restrict__ yout) {
  __shared__ __align__(16) u16 WtH[64 * 72], WtL[64 * 72];
  __shared__ __align__(16) u16 gzH[4][64 * 24], gzL[4][64 * 24];
  __shared__ __align__(16) float At[4][16 * 20];
  __shared__ float bsh[64];
  int bx = blockIdx.x;
  int n = bx & 127, h = bx >> 7;
  int tid = threadIdx.x, lane = tid & 63, wv = tid >> 6;
  int fr = lane & 15, qd = lane >> 4;

  {
    int e = tid >> 2, d0 = (tid & 3) << 4;
    const float* src = Wseq + (((size_t)h * 128 + n) * 64 + e) * 64 + d0;
#pragma unroll
    for (int gsub = 0; gsub < 2; ++gsub) {
      u16 hb[8], lb_[8];
#pragma unroll
      for (int i = 0; i < 8; i += 4) {
        float4 v = *(const float4*)(src + gsub * 8 + i);
        f2hl(v.x, hb[i], lb_[i]);
        f2hl(v.y, hb[i + 1], lb_[i + 1]);
        f2hl(v.z, hb[i + 2], lb_[i + 2]);
        f2hl(v.w, hb[i + 3], lb_[i + 3]);
      }
      uint4 ph, pl;
      ph.x = hb[0] | ((u32)hb[1] << 16); ph.y = hb[2] | ((u32)hb[3] << 16);
      ph.z = hb[4] | ((u32)hb[5] << 16); ph.w = hb[6] | ((u32)hb[7] << 16);
      pl.x = lb_[0] | ((u32)lb_[1] << 16); pl.y = lb_[2] | ((u32)lb_[3] << 16);
      pl.z = lb_[4] | ((u32)lb_[5] << 16); pl.w = lb_[6] | ((u32)lb_[7] << 16);
      *(uint4*)(&WtH[e * 72 + d0 + gsub * 8]) = ph;
      *(uint4*)(&WtL[e * 72 + d0 + gsub * 8]) = pl;
    }
    if (tid < 64) bsh[tid] = bseq[((size_t)h * 128 + n) * 64 + tid];
  }
  __syncthreads();

  const size_t bh = (size_t)(wv * 16 + h);
  const float* Qp = Qf + (bh * 2048 + (size_t)n * 16) * 64;
  const float* Kp = Kf + (bh * 2048 + (size_t)n * 16) * 64;
  const float* Vp = Vf + (bh * 2048 + (size_t)n * 16) * 64;
  const float* ep = eta + bh * 2048 + n * 16;

  short8 qH[2], qL[2], kH[2], kL[2];
#pragma unroll
  for (int s = 0; s < 2; ++s) {
    const float* p1 = Qp + fr * 64 + s * 32 + qd * 8;
    const float* p2 = Kp + fr * 64 + s * 32 + qd * 8;
#pragma unroll
    for (int j = 0; j < 8; ++j) {
      u16 hb, lb_;
      f2hl(p1[j], hb, lb_); qH[s][j] = (short)hb; qL[s][j] = (short)lb_;
      f2hl(p2[j], hb, lb_); kH[s][j] = (short)hb; kL[s][j] = (short)lb_;
    }
  }

  f32x4 Zt[4];
#pragma unroll
  for (int t = 0; t < 4; ++t) {
    f32x4 a = {0.f, 0.f, 0.f, 0.f};
#pragma unroll
    for (int s = 0; s < 2; ++s) {
      short8 wH = *(const short8*)(&WtH[(t * 16 + fr) * 72 + s * 32 + qd * 8]);
      short8 wL = *(const short8*)(&WtL[(t * 16 + fr) * 72 + s * 32 + qd * 8]);
      a = MFMA16(kH[s], wH, a);
      a = MFMA16(kL[s], wH, a);
      a = MFMA16(kH[s], wL, a);
    }
    float bv = bsh[t * 16 + fr];
    a[0] += bv; a[1] += bv; a[2] += bv; a[3] += bv;
    Zt[t] = a;
  }
  f32x4 Atn = {0.f, 0.f, 0.f, 0.f};
#pragma unroll
  for (int s = 0; s < 2; ++s) {
    Atn = MFMA16(qH[s], kH[s], Atn);
    Atn = MFMA16(qL[s], kH[s], Atn);
    Atn = MFMA16(qH[s], kL[s], Atn);
  }

  float gw[4], gb[4];
#pragma unroll
  for (int t = 0; t < 4; ++t) {
    gw[t] = ttt_w[h * 64 + t * 16 + fr];
    gb[t] = ttt_b[h * 64 + t * 16 + fr];
  }
  float s1[4], s2[4];
#pragma unroll
  for (int r = 0; r < 4; ++r) {
    float a0 = Zt[0][r], a1 = Zt[1][r], a2 = Zt[2][r], a3 = Zt[3][r];
    s1[r] = a0 + a1 + a2 + a3;
    s2[r] = a0 * a0 + a1 * a1 + a2 * a2 + a3 * a3;
  }
#pragma unroll
  for (int off = 1; off <= 8; off <<= 1) {
#pragma unroll
    for (int r = 0; r < 4; ++r) {
      s1[r] += __shfl_xor(s1[r], off, 64);
      s2[r] += __shfl_xor(s2[r], off, 64);
    }
  }
  float mu[4], rstd[4];
#pragma unroll
  for (int r = 0; r < 4; ++r) {
    mu[r] = s1[r] * 0.015625f;
    float var = s2[r] * 0.015625f - mu[r] * mu[r];
    rstd[r] = rsqrtf(var + 1e-5f);
  }
  float xc[4][4], gxn[4][4];
  float s3[4] = {0, 0, 0, 0}, s4[4] = {0, 0, 0, 0}, s5[4] = {0, 0, 0, 0};
#pragma unroll
  for (int t = 0; t < 4; ++t) {
#pragma unroll
    for (int r = 0; r < 4; ++r) {
      float z = Zt[t][r];
      float x = z - mu[r];
      xc[t][r] = x;
      float ln = x * rstd[r] * gw[t] + gb[t];
      float vV = Vp[(qd * 4 + r) * 64 + t * 16 + fr];
      float vK = Kp[(qd * 4 + r) * 64 + t * 16 + fr];
      float go = ln - (vV - vK);
      float gx = go * gw[t];
      gxn[t][r] = gx;
      s3[r] += gx * x;
      s4[r] += gx;
      s5[r] += x;
    }
  }
#pragma unroll
  for (int off = 1; off <= 8; off <<= 1) {
#pragma unroll
    for (int r = 0; r < 4; ++r) {
      s3[r] += __shfl_xor(s3[r], off, 64);
      s4[r] += __shfl_xor(s4[r], off, 64);
      s5[r] += __shfl_xor(s5[r], off, 64);
    }
  }
  float gvar[4], gmu[4];
#pragma unroll
  for (int r = 0; r < 4; ++r) {
    float r3 = rstd[r] * rstd[r] * rstd[r];
    gvar[r] = -0.5f * s3[r] * r3;
    gmu[r] = -s4[r] * rstd[r] + gvar[r] * (-2.0f * s5[r]) * 0.015625f;
  }
#pragma unroll
  for (int t = 0; t < 4; ++t) {
    u16 hb[4], lb_[4];
#pragma unroll
    for (int r = 0; r < 4; ++r) {
      float gz = gxn[t][r] * rstd[r] + gvar[r] * 2.0f * xc[t][r] * 0.015625f + gmu[r] * 0.015625f;
      f2hl(gz, hb[r], lb_[r]);
    }
    uint2 ph, pl;
    ph.x = hb[0] | ((u32)hb[1] << 16); ph.y = hb[2] | ((u32)hb[3] << 16);
    pl.x = lb_[0] | ((u32)lb_[1] << 16); pl.y = lb_[2] | ((u32)lb_[3] << 16);
    *(uint2*)(&gzH[wv][(t * 16 + fr) * 24 + qd * 4]) = ph;
    *(uint2*)(&gzL[wv][(t * 16 + fr) * 24 + qd * 4]) = pl;
  }
  *(f32x4*)(&At[wv][fr * 20 + qd * 4]) = Atn;

  float em = ep[fr];
  short8 aH = s8zero(), aL = s8zero();
  if (qd < 2) {
#pragma unroll
    for (int j = 0; j < 8; ++j) {
      int nn = qd * 8 + j;
      float av = 0.0f;
      if (nn <= fr) av = em * (1.0f + At[wv][nn * 20 + fr]);
      u16 hb, lb_;
      f2hl(av, hb, lb_);
      aH[j] = (short)hb;
      aL[j] = (short)lb_;
    }
  }
  f32x4 Ob[4];
#pragma unroll
  for (int t = 0; t < 4; ++t) {
    f32x4 a = {0.f, 0.f, 0.f, 0.f};
#pragma unroll
    for (int s = 0; s < 2; ++s) {
      short8 wH = *(const short8*)(&WtH[(t * 16 + fr) * 72 + s * 32 + qd * 8]);
      short8 wL = *(const short8*)(&WtL[(t * 16 + fr) * 72 + s * 32 + qd * 8]);
      a = MFMA16(qH[s], wH, a);
      a = MFMA16(qL[s], wH, a);
      a = MFMA16(qH[s], wL, a);
    }
    short8 gH = s8zero(), gL = s8zero();
    if (qd < 2) {
      gH = *(const short8*)(&gzH[wv][(t * 16 + fr) * 24 + qd * 8]);
      gL = *(const short8*)(&gzL[wv][(t * 16 + fr) * 24 + qd * 8]);
    }
    f32x4 c = {0.f, 0.f, 0.f, 0.f};
    c = MFMA16(aH, gH, c);
    c = MFMA16(aL, gH, c);
    c = MFMA16(aH, gL, c);
    float bv = bsh[t * 16 + fr];
#pragma unroll
    for (int r = 0; r < 4; ++r) Ob[t][r] = a[r] - c[r] + bv;
  }
#pragma unroll
  for (int r = 0; r < 4; ++r) {
    float a0 = Ob[0][r], a1 = Ob[1][r], a2 = Ob[2][r], a3 = Ob[3][r];
    s1[r] = a0 + a1 + a2 + a3;
    s2[r] = a0 * a0 + a1 * a1 + a2 * a2 + a3 * a3;
  }
#pragma unroll
  for (int off = 1; off <= 8; off <<= 1) {
#pragma unroll
    for (int r = 0; r < 4; ++r) {
      s1[r] += __shfl_xor(s1[r], off, 64);
      s2[r] += __shfl_xor(s2[r], off, 64);
    }
  }
#pragma unroll
  for (int r = 0; r < 4; ++r) {
    mu[r] = s1[r] * 0.015625f;
    float var = s2[r] * 0.015625f - mu[r] * mu[r];
    rstd[r] = rsqrtf(var + 1e-5f);
  }
#pragma unroll
  for (int t = 0; t < 4; ++t) {
#pragma unroll
    for (int r = 0; r < 4; ++r) {
      float ln = (Ob[t][r] - mu[r]) * rstd[r] * gw[t] + gb[t];
      float qv = Qp[(qd * 4 + r) * 64 + t * 16 + fr];
      yout[((size_t)wv * 2048 + n * 16 + qd * 4 + r) * 1024 + h * 64 + t * 16 + fr] = qv + ln;
    }
  }
}

// ---------- kernel 4: post-LN + gate -> zb (bf16) ----------
__global__ __launch_bounds__(256) void k_postln(
    const float* __restrict__ yf, const u16* __restrict__ gateb,
    const float* __restrict__ post_w, const float* __restrict__ post_b, u16* __restrict__ zb) {
  __shared__ float red[8];
  int row = blockIdx.x, tid = threadIdx.x;
  int lane = tid & 63, wid = tid >> 6;
  const float* yr = yf + (size_t)row * 1024;
  float4 v = *(const float4*)(yr + tid * 4);
  float s1 = v.x + v.y + v.z + v.w;
  float s2 = v.x * v.x + v.y * v.y + v.z * v.z + v.w * v.w;
  s1 = wsum64(s1);
  s2 = wsum64(s2);
  if (lane == 0) { red[wid] = s1; red[4 + wid] = s2; }
  __syncthreads();
  s1 = red[0] + red[1] + red[2] + red[3];
  s2 = red[4] + red[5] + red[6] + red[7];
  float mu = s1 * (1.0f / 1024.0f);
  float var = s2 * (1.0f / 1024.0f) - mu * mu;
  float rstd = rsqrtf(var + 1e-5f);
  float vals[4] = {v.x, v.y, v.z, v.w};
  u16 ov[4];
#pragma unroll
  for (int i = 0; i < 4; ++i) {
    int cc = tid * 4 + i;
    float yn = (vals[i] - mu) * rstd * post_w[cc] + post_b[cc];
    float gt = bf2f(gateb[(size_t)row * 1024 + cc]);
    ov[i] = f2bf(gt * yn);
  }
  ushort4 o;
  o.x = ov[0]; o.y = ov[1]; o.z = ov[2]; o.w = ov[3];
  *(ushort4*)(zb + (size_t)row * 1024 + tid * 4) = o;
}

// ---------- kernel 5: output GEMM ----------
__global__ __launch_bounds__(256) void k_gemm2(const u16* __restrict__ A, const u16* __restrict__ Bw,
                                               float* __restrict__ Out) {
  __shared__ __align__(16) u16 sA[128 * 40];
  __shared__ __align__(16) u16 sB[128 * 40];
  int bm = blockIdx.x & 63, bn = blockIdx.x >> 6;
  f32x4 acc[4][4];
  gemm_core(A, Bw, bm, bn, sA, sB, acc);
  int tid = threadIdx.x, lane = tid & 63, wid = tid >> 6;
  int fr = lane & 15, qd = lane >> 4;
  int wm = (wid & 1) * 64, wn = (wid >> 1) * 64;
#pragma unroll
  for (int i = 0; i < 4; ++i) {
    int gr0 = bm * 128 + wm + i * 16 + qd * 4;
#pragma unroll
    for (int j = 0; j < 4; ++j) {
      int gc = bn * 128 + wn + j * 16 + fr;
#pragma unroll
      for (int r = 0; r < 4; ++r) Out[(size_t)(gr0 + r) * 1024 + gc] = acc[i][j][r];
    }
  }
}

// ---------- workspace layout (bytes) ----------
#define OFF_XB    ((size_t)0)
#define OFF_WCAT  ((size_t)16777216)
#define OFF_WOB   ((size_t)25427968)
#define OFF_Q     ((size_t)27525120)
#define OFF_K     ((size_t)61079552)
#define OFF_V     ((size_t)94633984)
#define OFF_GATE  ((size_t)128188416)
#define OFF_ETA   ((size_t)144965632)
#define OFF_WSEQ  ((size_t)145489920)
#define OFF_BSEQ  ((size_t)179044352)
#define OFF_Y     ((size_t)179568640)
#define OFF_ZB    ((size_t)213123072)
// Klast/Vlast/etalast nest inside the ZB region (timeline-disjoint: dead
// before postln writes zb).
#define OFF_KL    OFF_ZB
#define OFF_VL    (OFF_ZB + 2097152)
#define OFF_EL    (OFF_ZB + 4194304)

extern "C" void kernel_launch(void* const* d_in, const int* in_sizes, int n_in,
                              void* d_out, int out_size, void* d_ws, size_t ws_size,
                              hipStream_t stream) {
  const float* x    = (const float*)d_in[0];
  const float* Wq   = (const float*)d_in[1];
  const float* Wk   = (const float*)d_in[2];
  const float* Wv   = (const float*)d_in[3];
  const float* Wini = (const float*)d_in[4];
  const float* bini = (const float*)d_in[5];
  const float* ttw  = (const float*)d_in[6];
  const float* ttb  = (const float*)d_in[7];
  const float* pw   = (const float*)d_in[8];
  const float* pb   = (const float*)d_in[9];
  const float* lrw  = (const float*)d_in[10];
  const float* lrb  = (const float*)d_in[11];
  const float* tio  = (const float*)d_in[12];
  const float* Wg   = (const float*)d_in[13];
  const float* Wo   = (const float*)d_in[14];
  (void)in_sizes; (void)n_in; (void)out_size; (void)ws_size;
  float* out = (float*)d_out;
  char* ws = (char*)d_ws;
  u16* xb    = (u16*)(ws + OFF_XB);
  u16* Wcat  = (u16*)(ws + OFF_WCAT);
  u16* Wob   = (u16*)(ws + OFF_WOB);
  float* Qf  = (float*)(ws + OFF_Q);
  float* Kf  = (float*)(ws + OFF_K);
  float* Vf  = (float*)(ws + OFF_V);
  u16* gateb = (u16*)(ws + OFF_GATE);
  float* eta = (float*)(ws + OFF_ETA);
  float* Wsq = (float*)(ws + OFF_WSEQ);
  float* bsq = (float*)(ws + OFF_BSEQ);
  float* yf  = (float*)(ws + OFF_Y);
  u16* zbuf  = (u16*)(ws + OFF_ZB);
  float* Klast   = (float*)(ws + OFF_KL);
  float* Vlast   = (float*)(ws + OFF_VL);
  float* etalast = (float*)(ws + OFF_EL);

  hipLaunchKernelGGL(k_cast, dim3(13440), dim3(256), 0, stream, x, Wq, Wk, Wv, Wg, lrw, Wo, xb, Wcat, Wob);
  hipLaunchKernelGGL(k_lastrow, dim3(68), dim3(256), 0, stream, xb, Wcat, Klast, Vlast, etalast, lrb, tio);
  hipLaunchKernelGGL(k_fused, dim3(560), dim3(1024), 0, stream, xb, Wcat, Qf, Kf, Vf, gateb, eta, lrb, tio,
                     Klast, Vlast, etalast, Wini, bini, ttw, ttb, Wsq, bsq);
  hipLaunchKernelGGL(k_phaseB, dim3(2048), dim3(256), 0, stream, Qf, Kf, Vf, eta, Wsq, bsq, ttw, ttb, yf);
  hipLaunchKernelGGL(k_postln, dim3(8192), dim3(256), 0, stream, yf, gateb, pw, pb, zbuf);
  hipLaunchKernelGGL(k_gemm2, dim3(64 * 8), dim3(256), 0, stream, zbuf, Wob, out);
}